// Round 1
// baseline (526.971 us; speedup 1.0000x reference)
//
#include <hip/hip_runtime.h>

typedef unsigned short u16;
typedef __attribute__((ext_vector_type(4))) float f32x4;
typedef __attribute__((ext_vector_type(8))) short s16x8;

#define SCALAR_F 0.08838834764831845f
#define KMASKF (-1e30f)

__device__ __forceinline__ u16 f2b(float f){
  unsigned u = __float_as_uint(f);
  unsigned r = u + 0x7FFFu + ((u>>16)&1u);
  return (u16)(r>>16);
}
__device__ __forceinline__ float b2f(u16 h){ return __uint_as_float(((unsigned)h)<<16); }

__device__ __forceinline__ f32x4 mfma16(s16x8 a, s16x8 b, f32x4 c){
  return __builtin_amdgcn_mfma_f32_16x16x32_bf16(a, b, c, 0, 0, 0);
}

__device__ __forceinline__ void glds16(const u16* g, u16* l){
  __builtin_amdgcn_global_load_lds((const __attribute__((address_space(1))) unsigned*)g,
                                   (__attribute__((address_space(3))) unsigned*)l, 16, 0, 0);
}

// ---------------- x f32 -> bf16 ----------------
__global__ __launch_bounds__(256) void cvt_f32_bf16(const float* __restrict__ in, u16* __restrict__ out){
  int i = blockIdx.x*256 + threadIdx.x;
  const float4* p = (const float4*)in;
  float4 a = p[2*i], b = p[2*i+1];
  s16x8 r;
  r[0]=(short)f2b(a.x); r[1]=(short)f2b(a.y); r[2]=(short)f2b(a.z); r[3]=(short)f2b(a.w);
  r[4]=(short)f2b(b.x); r[5]=(short)f2b(b.y); r[6]=(short)f2b(b.z); r[7]=(short)f2b(b.w);
  *(s16x8*)(out + (size_t)i*8) = r;
}

// ---------------- build combined qkv weight, B^T layout: wt[c][d], c in [0,4096) ----------------
__global__ __launch_bounds__(256) void build_wqkvt(const float* __restrict__ qw, const float* __restrict__ kvw,
                                                   u16* __restrict__ out){
  __shared__ float t[64][65];
  int head = blockIdx.z;            // 0..31: 16 q heads, 8 k heads, 8 v heads
  int d0 = blockIdx.y*64, h0 = blockIdx.x*64;
  const float* src; int colbase;
  if (head < 16){ src = qw + (size_t)head*2048*128; colbase = head*128; }
  else if (head < 24){ int k = head-16; src = kvw + (size_t)k*2048*128; colbase = 2048 + k*128; }
  else { int k = head-24; src = kvw + (size_t)(8+k)*2048*128; colbase = 3072 + k*128; }
  int tid = threadIdx.x;
  #pragma unroll
  for (int p=0;p<16;p++){ int e = p*256+tid; int r = e>>6, c = e&63;
    t[r][c] = src[(size_t)(d0+r)*128 + h0 + c]; }
  __syncthreads();
  #pragma unroll
  for (int p=0;p<16;p++){ int e = p*256+tid; int c = e>>6, r = e&63;
    out[(size_t)(colbase + h0 + c)*2048 + d0 + r] = f2b(t[r][c]); }
}

// ---------------- transpose o_w (2048x2048 f32) -> bf16 B^T ----------------
__global__ __launch_bounds__(256) void tr2048(const float* __restrict__ src, u16* __restrict__ out){
  __shared__ float t[64][65];
  int r0 = blockIdx.y*64, c0 = blockIdx.x*64;
  int tid = threadIdx.x;
  #pragma unroll
  for (int p=0;p<16;p++){ int e = p*256+tid; int r = e>>6, c = e&63;
    t[r][c] = src[(size_t)(r0+r)*2048 + c0 + c]; }
  __syncthreads();
  #pragma unroll
  for (int p=0;p<16;p++){ int e = p*256+tid; int c = e>>6, r = e&63;
    out[(size_t)(c0+c)*2048 + r0 + r] = f2b(t[r][c]); }
}

// ---------------- RoPE sin/cos table: table[pos][i] = (sin, cos) ----------------
__global__ __launch_bounds__(256) void rope_table(float* __restrict__ table){
  int tid = blockIdx.x*256 + threadIdx.x;     // 2048*64
  int pos = tid>>6, i = tid&63;
  float ts = powf(10000.f, (float)i * (1.f/64.f));
  float ang = (float)pos / ts;
  ((float2*)table)[tid] = make_float2(sinf(ang), cosf(ang));
}

// ---------------- GEMM: C[M,N] = A[M,K] * Bt[N,K]^T, bf16 in, f32 acc ----------------
template<bool OUTBF16>
__global__ __launch_bounds__(256) void gemm_bt(const u16* __restrict__ A, const u16* __restrict__ Bt,
                                               void* __restrict__ C, int K, int ldc){
  __shared__ u16 As[128*64];
  __shared__ u16 Bs[128*64];
  const int tid = threadIdx.x, w = tid>>6, l = tid&63;
  const int wm = w>>1, wn = w&1;
  const int l15 = l&15, lg = l>>4, l7 = l&7;
  const size_t m0 = (size_t)blockIdx.y*128, n0 = (size_t)blockIdx.x*128;
  const f32x4 z4 = {0.f,0.f,0.f,0.f};
  f32x4 acc[4][4];
  #pragma unroll
  for (int m=0;m<4;m++)
    #pragma unroll
    for (int n=0;n<4;n++) acc[m][n] = z4;
  const char* AsB = (const char*)As; const char* BsB = (const char*)Bs;
  int colsw[2];
  colsw[0] = (lg*16) ^ (l7<<4);
  colsw[1] = (64 + lg*16) ^ (l7<<4);
  int arow[4], brow[4];
  #pragma unroll
  for (int m=0;m<4;m++){ arow[m] = (wm*64 + m*16 + l15)*128; brow[m] = (wn*64 + m*16 + l15)*128; }
  const int sgl = l7 ^ (l>>3);  // staging pre-swizzled granule
  for (int k0=0;k0<K;k0+=64){
    #pragma unroll
    for (int i=0;i<4;i++){
      int slot = (w*4+i)*64 + l;
      int row = slot>>3;
      glds16(A  + (m0+row)*K + k0 + sgl*8, (u16*)As + slot*8);
      glds16(Bt + (n0+row)*K + k0 + sgl*8, (u16*)Bs + slot*8);
    }
    __syncthreads();
    #pragma unroll
    for (int kb=0;kb<2;kb++){
      s16x8 af[4], bf[4];
      #pragma unroll
      for (int m=0;m<4;m++) af[m] = *(const s16x8*)(AsB + arow[m] + colsw[kb]);
      #pragma unroll
      for (int n=0;n<4;n++) bf[n] = *(const s16x8*)(BsB + brow[n] + colsw[kb]);
      #pragma unroll
      for (int m=0;m<4;m++)
        #pragma unroll
        for (int n=0;n<4;n++)
          acc[m][n] = mfma16(af[m], bf[n], acc[m][n]);
    }
    __syncthreads();
  }
  #pragma unroll
  for (int m=0;m<4;m++)
    #pragma unroll
    for (int n=0;n<4;n++)
      #pragma unroll
      for (int r=0;r<4;r++){
        size_t row = m0 + wm*64 + m*16 + lg*4 + r;
        size_t col = n0 + wn*64 + n*16 + l15;
        if (OUTBF16) ((u16*)C)[row*ldc + col] = f2b(acc[m][n][r]);
        else ((float*)C)[row*ldc + col] = acc[m][n][r];
      }
}

// ---------------- fused RMSNorm + RoPE (+SCALAR for q) ----------------
// one wave per (b,t,head) row; lane l holds elems (l, l+64)
__global__ __launch_bounds__(256) void norm_rope(const u16* __restrict__ qkv, const float* __restrict__ table,
                                                 const float* __restrict__ scale, const int* __restrict__ segpos,
                                                 u16* __restrict__ dst, int nhl2, int colbase, float mult){
  int w = threadIdx.x>>6, l = threadIdx.x&63;
  int rid = blockIdx.x*4 + w;
  int bt = rid >> nhl2;
  int n  = rid & ((1<<nhl2)-1);
  int b = bt >> 11, t = bt & 2047;
  const u16* src = qkv + (size_t)bt*4096 + colbase + n*128;
  float x1 = b2f(src[l]), x2 = b2f(src[64+l]);
  float ss = x1*x1 + x2*x2;
  #pragma unroll
  for (int off=32; off; off>>=1) ss += __shfl_xor(ss, off);
  float rs = rsqrtf(ss*(1.f/128.f) + 1e-6f);
  float v1 = x1*rs*scale[l], v2 = x2*rs*scale[64+l];
  int pos = segpos[bt];
  float2 sc = ((const float2*)table)[pos*64 + l];
  float o1 = (v1*sc.y - v2*sc.x)*mult;
  float o2 = (v2*sc.y + v1*sc.x)*mult;
  u16* d = dst + (((size_t)((b<<nhl2) + n))*2048 + t)*128;
  d[l] = f2b(o1); d[64+l] = f2b(o2);
}

// ---------------- V transpose: vt[(b*8+kv)*128 + d][s] = qkv[b*T+s][3072+kv*128+d] ----------------
__global__ __launch_bounds__(256) void vtr(const u16* __restrict__ qkv, u16* __restrict__ vt){
  __shared__ float t[64][65];
  int bk = blockIdx.z;              // b*8+kv
  int t0 = blockIdx.y*64, d0 = blockIdx.x*64;
  int b = bk>>3, kv = bk&7;
  int tid = threadIdx.x;
  #pragma unroll
  for (int p=0;p<16;p++){ int e = p*256+tid; int r = e>>6, c = e&63;
    t[r][c] = b2f(qkv[(size_t)(b*2048 + t0 + r)*4096 + 3072 + kv*128 + d0 + c]); }
  __syncthreads();
  #pragma unroll
  for (int p=0;p<16;p++){ int e = p*256+tid; int c = e>>6, r = e&63;
    vt[((size_t)bk*128 + d0 + c)*2048 + t0 + r] = f2b(t[r][c]); }
}

// ---------------- flash attention, causal, GQA g=2 ----------------
__global__ __launch_bounds__(256) void attn_kern(const u16* __restrict__ qn, const u16* __restrict__ kn,
                                                 const u16* __restrict__ vt, u16* __restrict__ enc){
  __shared__ u16 Ks[64*128];   // [s][d], swizzled
  __shared__ u16 Vs[128*64];   // [d][s], swizzled
  __shared__ u16 Ps[4*32*64];  // per-wave P, swizzled
  const int t0 = blockIdx.x*128, hn = blockIdx.y, b = blockIdx.z;
  const int kv = hn>>1;
  const int tid = threadIdx.x, w = tid>>6, l = tid&63;
  const int l15 = l&15, lg = l>>4;
  const u16* qh = qn + ((size_t)(b*16+hn))*2048*128;
  const u16* kh = kn + ((size_t)(b*8+kv))*2048*128;
  const u16* vh = vt + ((size_t)(b*8+kv))*128*2048;
  const int qrb = t0 + w*32;

  s16x8 qf[2][4];
  #pragma unroll
  for (int m=0;m<2;m++)
    #pragma unroll
    for (int kb=0;kb<4;kb++)
      qf[m][kb] = *(const s16x8*)(qh + (size_t)(qrb + m*16 + l15)*128 + kb*32 + lg*8);

  const f32x4 z4 = {0.f,0.f,0.f,0.f};
  f32x4 o[2][8];
  #pragma unroll
  for (int m=0;m<2;m++)
    #pragma unroll
    for (int dn=0;dn<8;dn++) o[m][dn] = z4;
  float mrow[2][4], lp[2][4];
  #pragma unroll
  for (int m=0;m<2;m++)
    #pragma unroll
    for (int r=0;r<4;r++){ mrow[m][r] = KMASKF; lp[m][r] = 0.f; }

  const char* KsB = (const char*)Ks;
  const char* VsB = (const char*)Vs;
  char* PsB = (char*)Ps + w*4096;

  const int ntiles = (t0>>6) + 2;
  for (int it=0; it<ntiles; ++it){
    int s0 = it*64;
    #pragma unroll
    for (int i=0;i<4;i++){
      int slot = (w*4+i)*64 + l;
      { int row = slot>>4, g = slot&15, gl = g ^ (row&7);
        glds16(kh + (size_t)(s0+row)*128 + gl*8, Ks + slot*8); }
      { int row = slot>>3, g = slot&7, gl = g ^ (row&7);
        glds16(vh + (size_t)row*2048 + s0 + gl*8, Vs + slot*8); }
    }
    __syncthreads();

    f32x4 sa[2][4];
    #pragma unroll
    for (int m=0;m<2;m++)
      #pragma unroll
      for (int nc=0;nc<4;nc++) sa[m][nc] = z4;
    #pragma unroll
    for (int kb=0;kb<4;kb++){
      s16x8 kf[4];
      #pragma unroll
      for (int nc=0;nc<4;nc++){
        int srow = nc*16 + l15;
        int cb = (kb*64 + lg*16) ^ ((srow&7)<<4);
        kf[nc] = *(const s16x8*)(KsB + srow*256 + cb);
      }
      #pragma unroll
      for (int m=0;m<2;m++)
        #pragma unroll
        for (int nc=0;nc<4;nc++)
          sa[m][nc] = mfma16(qf[m][kb], kf[nc], sa[m][nc]);
    }
    if (s0 + 63 > qrb){
      #pragma unroll
      for (int m=0;m<2;m++)
        #pragma unroll
        for (int nc=0;nc<4;nc++)
          #pragma unroll
          for (int r=0;r<4;r++){
            int row = qrb + m*16 + lg*4 + r;
            int col = s0 + nc*16 + l15;
            if (col > row) sa[m][nc][r] = KMASKF;
          }
    }
    #pragma unroll
    for (int m=0;m<2;m++){
      #pragma unroll
      for (int r=0;r<4;r++){
        float pm = fmaxf(fmaxf(sa[m][0][r], sa[m][1][r]), fmaxf(sa[m][2][r], sa[m][3][r]));
        pm = fmaxf(pm, __shfl_xor(pm,1));
        pm = fmaxf(pm, __shfl_xor(pm,2));
        pm = fmaxf(pm, __shfl_xor(pm,4));
        pm = fmaxf(pm, __shfl_xor(pm,8));
        float mo = mrow[m][r];
        float mn = fmaxf(mo, pm);
        float sc = __expf(mo - mn);
        mrow[m][r] = mn;
        int rowp = m*16 + lg*4 + r;
        float ls = 0.f;
        #pragma unroll
        for (int nc=0;nc<4;nc++){
          float p = __expf(sa[m][nc][r] - mn);
          ls += p;
          int cb = ((nc*16 + l15)*2) ^ ((rowp&7)<<4);
          *(u16*)(PsB + rowp*128 + cb) = f2b(p);
        }
        lp[m][r] = lp[m][r]*sc + ls;
        #pragma unroll
        for (int dn=0;dn<8;dn++) o[m][dn][r] *= sc;
      }
    }
    asm volatile("" ::: "memory");   // order P ds_writes before PV ds_reads (same wave, no barrier needed)
    #pragma unroll
    for (int kb=0;kb<2;kb++){
      s16x8 pf[2];
      #pragma unroll
      for (int m=0;m<2;m++){
        int rowp = m*16 + l15;
        int cb = (kb*64 + lg*16) ^ ((rowp&7)<<4);
        pf[m] = *(const s16x8*)(PsB + rowp*128 + cb);
      }
      #pragma unroll
      for (int dn=0;dn<8;dn++){
        int vrow = dn*16 + l15;
        int cb = (kb*64 + lg*16) ^ ((vrow&7)<<4);
        s16x8 vf = *(const s16x8*)(VsB + vrow*128 + cb);
        o[0][dn] = mfma16(pf[0], vf, o[0][dn]);
        o[1][dn] = mfma16(pf[1], vf, o[1][dn]);
      }
    }
    __syncthreads();
  }
  // epilogue: normalize and store enc[b*T+t][hn*128+d]
  #pragma unroll
  for (int m=0;m<2;m++)
    #pragma unroll
    for (int r=0;r<4;r++){
      float s = lp[m][r];
      s += __shfl_xor(s,1); s += __shfl_xor(s,2); s += __shfl_xor(s,4); s += __shfl_xor(s,8);
      lp[m][r] = 1.f/s;
    }
  #pragma unroll
  for (int m=0;m<2;m++)
    #pragma unroll
    for (int dn=0;dn<8;dn++)
      #pragma unroll
      for (int r=0;r<4;r++){
        size_t row = (size_t)b*2048 + qrb + m*16 + lg*4 + r;
        size_t col = hn*128 + dn*16 + l15;
        enc[row*2048 + col] = f2b(o[m][dn][r]*lp[m][r]);
      }
}

extern "C" void kernel_launch(void* const* d_in, const int* in_sizes, int n_in,
                              void* d_out, int out_size, void* d_ws, size_t ws_size,
                              hipStream_t stream){
  const float* x      = (const float*)d_in[0];
  const int*   segpos = (const int*)d_in[1];
  // d_in[2] = attn_mask: structurally causal (tril) — handled analytically in attn_kern
  const float* qw     = (const float*)d_in[3];
  const float* kvw    = (const float*)d_in[4];
  const float* ow     = (const float*)d_in[5];
  const float* qs     = (const float*)d_in[6];
  const float* ks     = (const float*)d_in[7];
  float* out = (float*)d_out;

  char* ws = (char*)d_ws;
  size_t off = 0;
  auto alloc = [&](size_t bytes)->void*{ void* p = ws + off; off += (bytes + 255) & ~(size_t)255; return p; };
  u16*   xb    = (u16*)alloc((size_t)4096*2048*2);    // x bf16
  u16*   wqkvt = (u16*)alloc((size_t)4096*2048*2);    // combined qkv weight, B^T
  u16*   wot   = (u16*)alloc((size_t)2048*2048*2);    // o_w^T
  u16*   qkv   = (u16*)alloc((size_t)4096*4096*2);    // qkv projections bf16
  u16*   qn    = (u16*)alloc((size_t)2*16*2048*128*2);// normed+roped q (SCALAR folded)
  u16*   kn    = (u16*)alloc((size_t)2*8*2048*128*2); // normed+roped k
  u16*   vt    = (u16*)alloc((size_t)2*8*128*2048*2); // v transposed [d][s]
  u16*   enc   = (u16*)alloc((size_t)4096*2048*2);    // attention output bf16
  float* table = (float*)alloc((size_t)2048*64*2*4);  // rope sin/cos

  cvt_f32_bf16<<<4096,256,0,stream>>>(x, xb);
  build_wqkvt<<<dim3(2,32,32),256,0,stream>>>(qw, kvw, wqkvt);
  tr2048<<<dim3(32,32),256,0,stream>>>(ow, wot);
  rope_table<<<512,256,0,stream>>>(table);
  gemm_bt<true><<<dim3(32,32),256,0,stream>>>(xb, wqkvt, qkv, 2048, 4096);     // bf16 out
  norm_rope<<<16384,256,0,stream>>>(qkv, table, qs, segpos, qn, 4, 0,    SCALAR_F);
  norm_rope<<<8192, 256,0,stream>>>(qkv, table, ks, segpos, kn, 3, 2048, 1.0f);
  vtr<<<dim3(2,32,16),256,0,stream>>>(qkv, vt);
  attn_kern<<<dim3(16,16,2),256,0,stream>>>(qn, kn, vt, enc);
  gemm_bt<false><<<dim3(16,32),256,0,stream>>>(enc, wot, out, 2048, 2048);     // f32 out
}

// Round 2
// 438.049 us; speedup vs baseline: 1.2030x; 1.2030x over previous
//
#include <hip/hip_runtime.h>

typedef unsigned short u16;
typedef __attribute__((ext_vector_type(4))) float f32x4;
typedef __attribute__((ext_vector_type(8))) short s16x8;

#define SCALAR_F 0.08838834764831845f
#define KMASKF (-1e30f)

__device__ __forceinline__ u16 f2b(float f){
  unsigned u = __float_as_uint(f);
  unsigned r = u + 0x7FFFu + ((u>>16)&1u);
  return (u16)(r>>16);
}
__device__ __forceinline__ float b2f(u16 h){ return __uint_as_float(((unsigned)h)<<16); }

__device__ __forceinline__ f32x4 mfma16(s16x8 a, s16x8 b, f32x4 c){
  return __builtin_amdgcn_mfma_f32_16x16x32_bf16(a, b, c, 0, 0, 0);
}

__device__ __forceinline__ void glds16(const u16* g, u16* l){
  __builtin_amdgcn_global_load_lds((const __attribute__((address_space(1))) unsigned*)g,
                                   (__attribute__((address_space(3))) unsigned*)l, 16, 0, 0);
}

// ---------------- x f32 -> bf16 ----------------
__global__ __launch_bounds__(256) void cvt_f32_bf16(const float* __restrict__ in, u16* __restrict__ out){
  int i = blockIdx.x*256 + threadIdx.x;
  const float4* p = (const float4*)in;
  float4 a = p[2*i], b = p[2*i+1];
  s16x8 r;
  r[0]=(short)f2b(a.x); r[1]=(short)f2b(a.y); r[2]=(short)f2b(a.z); r[3]=(short)f2b(a.w);
  r[4]=(short)f2b(b.x); r[5]=(short)f2b(b.y); r[6]=(short)f2b(b.z); r[7]=(short)f2b(b.w);
  *(s16x8*)(out + (size_t)i*8) = r;
}

// ---------------- build combined qkv weight, B^T layout: wt[c][d], c in [0,4096) ----------------
__global__ __launch_bounds__(256) void build_wqkvt(const float* __restrict__ qw, const float* __restrict__ kvw,
                                                   u16* __restrict__ out){
  __shared__ float t[64][65];
  int head = blockIdx.z;            // 0..31: 16 q heads, 8 k heads, 8 v heads
  int d0 = blockIdx.y*64, h0 = blockIdx.x*64;
  const float* src; int colbase;
  if (head < 16){ src = qw + (size_t)head*2048*128; colbase = head*128; }
  else if (head < 24){ int k = head-16; src = kvw + (size_t)k*2048*128; colbase = 2048 + k*128; }
  else { int k = head-24; src = kvw + (size_t)(8+k)*2048*128; colbase = 3072 + k*128; }
  int tid = threadIdx.x;
  #pragma unroll
  for (int p=0;p<16;p++){ int e = p*256+tid; int r = e>>6, c = e&63;
    t[r][c] = src[(size_t)(d0+r)*128 + h0 + c]; }
  __syncthreads();
  #pragma unroll
  for (int p=0;p<16;p++){ int e = p*256+tid; int c = e>>6, r = e&63;
    out[(size_t)(colbase + h0 + c)*2048 + d0 + r] = f2b(t[r][c]); }
}

// ---------------- transpose o_w (2048x2048 f32) -> bf16 B^T ----------------
__global__ __launch_bounds__(256) void tr2048(const float* __restrict__ src, u16* __restrict__ out){
  __shared__ float t[64][65];
  int r0 = blockIdx.y*64, c0 = blockIdx.x*64;
  int tid = threadIdx.x;
  #pragma unroll
  for (int p=0;p<16;p++){ int e = p*256+tid; int r = e>>6, c = e&63;
    t[r][c] = src[(size_t)(r0+r)*2048 + c0 + c]; }
  __syncthreads();
  #pragma unroll
  for (int p=0;p<16;p++){ int e = p*256+tid; int c = e>>6, r = e&63;
    out[(size_t)(c0+c)*2048 + r0 + r] = f2b(t[r][c]); }
}

// ---------------- RoPE sin/cos table: table[pos][i] = (sin, cos) ----------------
__global__ __launch_bounds__(256) void rope_table(float* __restrict__ table){
  int tid = blockIdx.x*256 + threadIdx.x;     // 2048*64
  int pos = tid>>6, i = tid&63;
  float ts = powf(10000.f, (float)i * (1.f/64.f));
  float ang = (float)pos / ts;
  ((float2*)table)[tid] = make_float2(sinf(ang), cosf(ang));
}

// ---------------- GEMM: C[M,N] = A[M,K] * Bt[N,K]^T, bf16 in, f32 acc ----------------
template<bool OUTBF16>
__global__ __launch_bounds__(256) void gemm_bt(const u16* __restrict__ A, const u16* __restrict__ Bt,
                                               void* __restrict__ C, int K, int ldc){
  __shared__ u16 As[128*64];
  __shared__ u16 Bs[128*64];
  const int tid = threadIdx.x, w = tid>>6, l = tid&63;
  const int wm = w>>1, wn = w&1;
  const int l15 = l&15, lg = l>>4, l7 = l&7;
  const size_t m0 = (size_t)blockIdx.y*128, n0 = (size_t)blockIdx.x*128;
  const f32x4 z4 = {0.f,0.f,0.f,0.f};
  f32x4 acc[4][4];
  #pragma unroll
  for (int m=0;m<4;m++)
    #pragma unroll
    for (int n=0;n<4;n++) acc[m][n] = z4;
  const char* AsB = (const char*)As; const char* BsB = (const char*)Bs;
  int colsw[2];
  colsw[0] = (lg*16) ^ (l7<<4);
  colsw[1] = (64 + lg*16) ^ (l7<<4);
  int arow[4], brow[4];
  #pragma unroll
  for (int m=0;m<4;m++){ arow[m] = (wm*64 + m*16 + l15)*128; brow[m] = (wn*64 + m*16 + l15)*128; }
  const int sgl = l7 ^ (l>>3);  // staging pre-swizzled granule
  for (int k0=0;k0<K;k0+=64){
    #pragma unroll
    for (int i=0;i<4;i++){
      int slot = (w*4+i)*64 + l;
      int row = slot>>3;
      glds16(A  + (m0+row)*K + k0 + sgl*8, (u16*)As + slot*8);
      glds16(Bt + (n0+row)*K + k0 + sgl*8, (u16*)Bs + slot*8);
    }
    __syncthreads();
    #pragma unroll
    for (int kb=0;kb<2;kb++){
      s16x8 af[4], bf[4];
      #pragma unroll
      for (int m=0;m<4;m++) af[m] = *(const s16x8*)(AsB + arow[m] + colsw[kb]);
      #pragma unroll
      for (int n=0;n<4;n++) bf[n] = *(const s16x8*)(BsB + brow[n] + colsw[kb]);
      #pragma unroll
      for (int m=0;m<4;m++)
        #pragma unroll
        for (int n=0;n<4;n++)
          acc[m][n] = mfma16(af[m], bf[n], acc[m][n]);
    }
    __syncthreads();
  }
  #pragma unroll
  for (int m=0;m<4;m++)
    #pragma unroll
    for (int n=0;n<4;n++)
      #pragma unroll
      for (int r=0;r<4;r++){
        size_t row = m0 + wm*64 + m*16 + lg*4 + r;
        size_t col = n0 + wn*64 + n*16 + l15;
        if (OUTBF16) ((u16*)C)[row*ldc + col] = f2b(acc[m][n][r]);
        else ((float*)C)[row*ldc + col] = acc[m][n][r];
      }
}

// ---------------- fused RMSNorm + RoPE (+SCALAR for q) ----------------
// one wave per (b,t,head) row; lane l holds elems (l, l+64)
__global__ __launch_bounds__(256) void norm_rope(const u16* __restrict__ qkv, const float* __restrict__ table,
                                                 const float* __restrict__ scale, const int* __restrict__ segpos,
                                                 u16* __restrict__ dst, int nhl2, int colbase, float mult){
  int w = threadIdx.x>>6, l = threadIdx.x&63;
  int rid = blockIdx.x*4 + w;
  int bt = rid >> nhl2;
  int n  = rid & ((1<<nhl2)-1);
  int b = bt >> 11, t = bt & 2047;
  const u16* src = qkv + (size_t)bt*4096 + colbase + n*128;
  float x1 = b2f(src[l]), x2 = b2f(src[64+l]);
  float ss = x1*x1 + x2*x2;
  #pragma unroll
  for (int off=32; off; off>>=1) ss += __shfl_xor(ss, off);
  float rs = rsqrtf(ss*(1.f/128.f) + 1e-6f);
  float v1 = x1*rs*scale[l], v2 = x2*rs*scale[64+l];
  int pos = segpos[bt];
  float2 sc = ((const float2*)table)[pos*64 + l];
  float o1 = (v1*sc.y - v2*sc.x)*mult;
  float o2 = (v2*sc.y + v1*sc.x)*mult;
  u16* d = dst + (((size_t)((b<<nhl2) + n))*2048 + t)*128;
  d[l] = f2b(o1); d[64+l] = f2b(o2);
}

// ---------------- V transpose: vt[(b*8+kv)*128 + d][s] = qkv[b*T+s][3072+kv*128+d] ----------------
__global__ __launch_bounds__(256) void vtr(const u16* __restrict__ qkv, u16* __restrict__ vt){
  __shared__ float t[64][65];
  int bk = blockIdx.z;              // b*8+kv
  int t0 = blockIdx.y*64, d0 = blockIdx.x*64;
  int b = bk>>3, kv = bk&7;
  int tid = threadIdx.x;
  #pragma unroll
  for (int p=0;p<16;p++){ int e = p*256+tid; int r = e>>6, c = e&63;
    t[r][c] = b2f(qkv[(size_t)(b*2048 + t0 + r)*4096 + 3072 + kv*128 + d0 + c]); }
  __syncthreads();
  #pragma unroll
  for (int p=0;p<16;p++){ int e = p*256+tid; int c = e>>6, r = e&63;
    vt[((size_t)bk*128 + d0 + c)*2048 + t0 + r] = f2b(t[r][c]); }
}

// ---------------- flash attention, causal, GQA g=2 ----------------
// block: 256 threads = 4 waves; Q tile = 64 rows (16/wave); KV tile = 64.
// grid: 1024 blocks, LPT order (longest q-tiles dispatched first).
__global__ __launch_bounds__(256,4) void attn_kern(const u16* __restrict__ qn, const u16* __restrict__ kn,
                                                   const u16* __restrict__ vt, u16* __restrict__ enc){
  __shared__ u16 Ks[64*128];   // [s][d], swizzled
  __shared__ u16 Vs[128*64];   // [d][s], swizzled
  __shared__ u16 Ps[4*16*64];  // per-wave P, swizzled
  const int idx = blockIdx.x;
  const int qb = 31 - (idx>>5);        // longest first
  const int hb = idx & 31;
  const int hn = hb & 15, b = hb >> 4;
  const int t0 = qb*64;
  const int kv = hn>>1;
  const int tid = threadIdx.x, w = tid>>6, l = tid&63;
  const int l15 = l&15, lg = l>>4;
  const u16* qh = qn + ((size_t)(b*16+hn))*2048*128;
  const u16* kh = kn + ((size_t)(b*8+kv))*2048*128;
  const u16* vh = vt + ((size_t)(b*8+kv))*128*2048;
  const int qr0 = t0 + w*16;

  s16x8 qf[4];
  #pragma unroll
  for (int kb=0;kb<4;kb++)
    qf[kb] = *(const s16x8*)(qh + (size_t)(qr0 + l15)*128 + kb*32 + lg*8);

  const f32x4 z4 = {0.f,0.f,0.f,0.f};
  f32x4 o[8];
  #pragma unroll
  for (int dn=0;dn<8;dn++) o[dn] = z4;
  float mrow[4], lp[4];
  #pragma unroll
  for (int r=0;r<4;r++){ mrow[r] = KMASKF; lp[r] = 0.f; }

  const char* KsB = (const char*)Ks;
  const char* VsB = (const char*)Vs;
  char* PsB = (char*)Ps + w*2048;

  const int ntiles = qb + 1;
  for (int it=0; it<ntiles; ++it){
    int s0 = it*64;
    #pragma unroll
    for (int i=0;i<4;i++){
      int slot = (w*4+i)*64 + l;
      { int row = slot>>4, g = slot&15, gl = g ^ (row&7);
        glds16(kh + (size_t)(s0+row)*128 + gl*8, Ks + slot*8); }
      { int row = slot>>3, g = slot&7, gl = g ^ (row&7);
        glds16(vh + (size_t)row*2048 + s0 + gl*8, Vs + slot*8); }
    }
    __syncthreads();

    f32x4 sa[4];
    #pragma unroll
    for (int nc=0;nc<4;nc++) sa[nc] = z4;
    #pragma unroll
    for (int kb=0;kb<4;kb++){
      s16x8 kf[4];
      #pragma unroll
      for (int nc=0;nc<4;nc++){
        int srow = nc*16 + l15;
        int cb = (kb*64 + lg*16) ^ ((srow&7)<<4);
        kf[nc] = *(const s16x8*)(KsB + srow*256 + cb);
      }
      #pragma unroll
      for (int nc=0;nc<4;nc++)
        sa[nc] = mfma16(qf[kb], kf[nc], sa[nc]);
    }
    if (it == ntiles-1){
      #pragma unroll
      for (int nc=0;nc<4;nc++)
        #pragma unroll
        for (int r=0;r<4;r++){
          int row = qr0 + lg*4 + r;
          int col = s0 + nc*16 + l15;
          if (col > row) sa[nc][r] = KMASKF;
        }
    }
    #pragma unroll
    for (int r=0;r<4;r++){
      float pm = fmaxf(fmaxf(sa[0][r], sa[1][r]), fmaxf(sa[2][r], sa[3][r]));
      pm = fmaxf(pm, __shfl_xor(pm,1));
      pm = fmaxf(pm, __shfl_xor(pm,2));
      pm = fmaxf(pm, __shfl_xor(pm,4));
      pm = fmaxf(pm, __shfl_xor(pm,8));
      float mo = mrow[r];
      float mn = fmaxf(mo, pm);
      float sc = __expf(mo - mn);
      mrow[r] = mn;
      int rowp = lg*4 + r;
      float ls = 0.f;
      #pragma unroll
      for (int nc=0;nc<4;nc++){
        float p = __expf(sa[nc][r] - mn);
        ls += p;
        int cb = ((nc*16 + l15)*2) ^ ((rowp&7)<<4);
        *(u16*)(PsB + rowp*128 + cb) = f2b(p);
      }
      lp[r] = lp[r]*sc + ls;
      #pragma unroll
      for (int dn=0;dn<8;dn++) o[dn][r] *= sc;
    }
    asm volatile("" ::: "memory");   // order P ds_writes before PV ds_reads (same wave, no barrier needed)
    #pragma unroll
    for (int kb=0;kb<2;kb++){
      int rowp = l15;
      int cbp = (kb*64 + lg*16) ^ ((rowp&7)<<4);
      s16x8 pf = *(const s16x8*)(PsB + rowp*128 + cbp);
      #pragma unroll
      for (int dn=0;dn<8;dn++){
        int vrow = dn*16 + l15;
        int cb = (kb*64 + lg*16) ^ ((vrow&7)<<4);
        s16x8 vf = *(const s16x8*)(VsB + vrow*128 + cb);
        o[dn] = mfma16(pf, vf, o[dn]);
      }
    }
    __syncthreads();
  }
  // epilogue: normalize and store enc[b*T+t][hn*128+d]
  #pragma unroll
  for (int r=0;r<4;r++){
    float s = lp[r];
    s += __shfl_xor(s,1); s += __shfl_xor(s,2); s += __shfl_xor(s,4); s += __shfl_xor(s,8);
    lp[r] = 1.f/s;
  }
  #pragma unroll
  for (int dn=0;dn<8;dn++)
    #pragma unroll
    for (int r=0;r<4;r++){
      size_t row = (size_t)b*2048 + qr0 + lg*4 + r;
      size_t col = hn*128 + dn*16 + l15;
      enc[row*2048 + col] = f2b(o[dn][r]*lp[r]);
    }
}

extern "C" void kernel_launch(void* const* d_in, const int* in_sizes, int n_in,
                              void* d_out, int out_size, void* d_ws, size_t ws_size,
                              hipStream_t stream){
  const float* x      = (const float*)d_in[0];
  const int*   segpos = (const int*)d_in[1];
  // d_in[2] = attn_mask: structurally causal (tril) — handled analytically in attn_kern
  const float* qw     = (const float*)d_in[3];
  const float* kvw    = (const float*)d_in[4];
  const float* ow     = (const float*)d_in[5];
  const float* qs     = (const float*)d_in[6];
  const float* ks     = (const float*)d_in[7];
  float* out = (float*)d_out;

  char* ws = (char*)d_ws;
  size_t off = 0;
  auto alloc = [&](size_t bytes)->void*{ void* p = ws + off; off += (bytes + 255) & ~(size_t)255; return p; };
  u16*   xb    = (u16*)alloc((size_t)4096*2048*2);    // x bf16
  u16*   wqkvt = (u16*)alloc((size_t)4096*2048*2);    // combined qkv weight, B^T
  u16*   wot   = (u16*)alloc((size_t)2048*2048*2);    // o_w^T
  u16*   qkv   = (u16*)alloc((size_t)4096*4096*2);    // qkv projections bf16
  u16*   qn    = (u16*)alloc((size_t)2*16*2048*128*2);// normed+roped q (SCALAR folded)
  u16*   kn    = (u16*)alloc((size_t)2*8*2048*128*2); // normed+roped k
  u16*   vt    = (u16*)alloc((size_t)2*8*128*2048*2); // v transposed [d][s]
  u16*   enc   = (u16*)alloc((size_t)4096*2048*2);    // attention output bf16
  float* table = (float*)alloc((size_t)2048*64*2*4);  // rope sin/cos

  cvt_f32_bf16<<<4096,256,0,stream>>>(x, xb);
  build_wqkvt<<<dim3(2,32,32),256,0,stream>>>(qw, kvw, wqkvt);
  tr2048<<<dim3(32,32),256,0,stream>>>(ow, wot);
  rope_table<<<512,256,0,stream>>>(table);
  gemm_bt<true><<<dim3(32,32),256,0,stream>>>(xb, wqkvt, qkv, 2048, 4096);     // bf16 out
  norm_rope<<<16384,256,0,stream>>>(qkv, table, qs, segpos, qn, 4, 0,    SCALAR_F);
  norm_rope<<<8192, 256,0,stream>>>(qkv, table, ks, segpos, kn, 3, 2048, 1.0f);
  vtr<<<dim3(2,32,16),256,0,stream>>>(qkv, vt);
  attn_kern<<<1024,256,0,stream>>>(qn, kn, vt, enc);
  gemm_bt<false><<<dim3(16,32),256,0,stream>>>(enc, wot, out, 2048, 2048);     // f32 out
}

// Round 3
// 384.667 us; speedup vs baseline: 1.3699x; 1.1388x over previous
//
#include <hip/hip_runtime.h>

typedef unsigned short u16;
typedef __attribute__((ext_vector_type(4))) float f32x4;
typedef __attribute__((ext_vector_type(8))) short s16x8;

#define SCALAR_F 0.08838834764831845f
#define KMASKF (-1e30f)

__device__ __forceinline__ u16 f2b(float f){
  unsigned u = __float_as_uint(f);
  unsigned r = u + 0x7FFFu + ((u>>16)&1u);
  return (u16)(r>>16);
}
__device__ __forceinline__ float b2f(u16 h){ return __uint_as_float(((unsigned)h)<<16); }

__device__ __forceinline__ f32x4 mfma16(s16x8 a, s16x8 b, f32x4 c){
  return __builtin_amdgcn_mfma_f32_16x16x32_bf16(a, b, c, 0, 0, 0);
}

__device__ __forceinline__ void glds16(const u16* g, u16* l){
  __builtin_amdgcn_global_load_lds((const __attribute__((address_space(1))) unsigned*)g,
                                   (__attribute__((address_space(3))) unsigned*)l, 16, 0, 0);
}

// ---------------- x f32 -> bf16 ----------------
__global__ __launch_bounds__(256) void cvt_f32_bf16(const float* __restrict__ in, u16* __restrict__ out){
  int i = blockIdx.x*256 + threadIdx.x;
  const float4* p = (const float4*)in;
  float4 a = p[2*i], b = p[2*i+1];
  s16x8 r;
  r[0]=(short)f2b(a.x); r[1]=(short)f2b(a.y); r[2]=(short)f2b(a.z); r[3]=(short)f2b(a.w);
  r[4]=(short)f2b(b.x); r[5]=(short)f2b(b.y); r[6]=(short)f2b(b.z); r[7]=(short)f2b(b.w);
  *(s16x8*)(out + (size_t)i*8) = r;
}

// ---------------- build combined qkv weight, B^T layout: wt[c][d], c in [0,4096) ----------------
__global__ __launch_bounds__(256) void build_wqkvt(const float* __restrict__ qw, const float* __restrict__ kvw,
                                                   u16* __restrict__ out){
  __shared__ float t[64][65];
  int head = blockIdx.z;            // 0..31: 16 q heads, 8 k heads, 8 v heads
  int d0 = blockIdx.y*64, h0 = blockIdx.x*64;
  const float* src; int colbase;
  if (head < 16){ src = qw + (size_t)head*2048*128; colbase = head*128; }
  else if (head < 24){ int k = head-16; src = kvw + (size_t)k*2048*128; colbase = 2048 + k*128; }
  else { int k = head-24; src = kvw + (size_t)(8+k)*2048*128; colbase = 3072 + k*128; }
  int tid = threadIdx.x;
  #pragma unroll
  for (int p=0;p<16;p++){ int e = p*256+tid; int r = e>>6, c = e&63;
    t[r][c] = src[(size_t)(d0+r)*128 + h0 + c]; }
  __syncthreads();
  #pragma unroll
  for (int p=0;p<16;p++){ int e = p*256+tid; int c = e>>6, r = e&63;
    out[(size_t)(colbase + h0 + c)*2048 + d0 + r] = f2b(t[r][c]); }
}

// ---------------- transpose o_w (2048x2048 f32) -> bf16 B^T ----------------
__global__ __launch_bounds__(256) void tr2048(const float* __restrict__ src, u16* __restrict__ out){
  __shared__ float t[64][65];
  int r0 = blockIdx.y*64, c0 = blockIdx.x*64;
  int tid = threadIdx.x;
  #pragma unroll
  for (int p=0;p<16;p++){ int e = p*256+tid; int r = e>>6, c = e&63;
    t[r][c] = src[(size_t)(r0+r)*2048 + c0 + c]; }
  __syncthreads();
  #pragma unroll
  for (int p=0;p<16;p++){ int e = p*256+tid; int c = e>>6, r = e&63;
    out[(size_t)(c0+c)*2048 + r0 + r] = f2b(t[r][c]); }
}

// ---------------- RoPE sin/cos table: table[pos][i] = (sin, cos) ----------------
__global__ __launch_bounds__(256) void rope_table(float* __restrict__ table){
  int tid = blockIdx.x*256 + threadIdx.x;     // 2048*64
  int pos = tid>>6, i = tid&63;
  float ts = powf(10000.f, (float)i * (1.f/64.f));
  float ang = (float)pos / ts;
  ((float2*)table)[tid] = make_float2(sinf(ang), cosf(ang));
}

// ---------------- GEMM: C[M,N] = A[M,K] * Bt[N,K]^T, bf16 in, f32 acc ----------------
template<bool OUTBF16>
__global__ __launch_bounds__(256) void gemm_bt(const u16* __restrict__ A, const u16* __restrict__ Bt,
                                               void* __restrict__ C, int K, int ldc){
  __shared__ u16 As[128*64];
  __shared__ u16 Bs[128*64];
  const int tid = threadIdx.x, w = tid>>6, l = tid&63;
  const int wm = w>>1, wn = w&1;
  const int l15 = l&15, lg = l>>4, l7 = l&7;
  const size_t m0 = (size_t)blockIdx.y*128, n0 = (size_t)blockIdx.x*128;
  const f32x4 z4 = {0.f,0.f,0.f,0.f};
  f32x4 acc[4][4];
  #pragma unroll
  for (int m=0;m<4;m++)
    #pragma unroll
    for (int n=0;n<4;n++) acc[m][n] = z4;
  const char* AsB = (const char*)As; const char* BsB = (const char*)Bs;
  int colsw[2];
  colsw[0] = (lg*16) ^ (l7<<4);
  colsw[1] = (64 + lg*16) ^ (l7<<4);
  int arow[4], brow[4];
  #pragma unroll
  for (int m=0;m<4;m++){ arow[m] = (wm*64 + m*16 + l15)*128; brow[m] = (wn*64 + m*16 + l15)*128; }
  const int sgl = l7 ^ (l>>3);  // staging pre-swizzled granule
  for (int k0=0;k0<K;k0+=64){
    #pragma unroll
    for (int i=0;i<4;i++){
      int slot = (w*4+i)*64 + l;
      int row = slot>>3;
      glds16(A  + (m0+row)*K + k0 + sgl*8, (u16*)As + slot*8);
      glds16(Bt + (n0+row)*K + k0 + sgl*8, (u16*)Bs + slot*8);
    }
    __syncthreads();
    #pragma unroll
    for (int kb=0;kb<2;kb++){
      s16x8 af[4], bf[4];
      #pragma unroll
      for (int m=0;m<4;m++) af[m] = *(const s16x8*)(AsB + arow[m] + colsw[kb]);
      #pragma unroll
      for (int n=0;n<4;n++) bf[n] = *(const s16x8*)(BsB + brow[n] + colsw[kb]);
      #pragma unroll
      for (int m=0;m<4;m++)
        #pragma unroll
        for (int n=0;n<4;n++)
          acc[m][n] = mfma16(af[m], bf[n], acc[m][n]);
    }
    __syncthreads();
  }
  #pragma unroll
  for (int m=0;m<4;m++)
    #pragma unroll
    for (int n=0;n<4;n++)
      #pragma unroll
      for (int r=0;r<4;r++){
        size_t row = m0 + wm*64 + m*16 + lg*4 + r;
        size_t col = n0 + wn*64 + n*16 + l15;
        if (OUTBF16) ((u16*)C)[row*ldc + col] = f2b(acc[m][n][r]);
        else ((float*)C)[row*ldc + col] = acc[m][n][r];
      }
}

// ---------------- fused RMSNorm + RoPE (+SCALAR for q) ----------------
// one wave per (b,t,head) row; lane l holds elems (l, l+64)
__global__ __launch_bounds__(256) void norm_rope(const u16* __restrict__ qkv, const float* __restrict__ table,
                                                 const float* __restrict__ scale, const int* __restrict__ segpos,
                                                 u16* __restrict__ dst, int nhl2, int colbase, float mult){
  int w = threadIdx.x>>6, l = threadIdx.x&63;
  int rid = blockIdx.x*4 + w;
  int bt = rid >> nhl2;
  int n  = rid & ((1<<nhl2)-1);
  int b = bt >> 11, t = bt & 2047;
  const u16* src = qkv + (size_t)bt*4096 + colbase + n*128;
  float x1 = b2f(src[l]), x2 = b2f(src[64+l]);
  float ss = x1*x1 + x2*x2;
  #pragma unroll
  for (int off=32; off; off>>=1) ss += __shfl_xor(ss, off);
  float rs = rsqrtf(ss*(1.f/128.f) + 1e-6f);
  float v1 = x1*rs*scale[l], v2 = x2*rs*scale[64+l];
  int pos = segpos[bt];
  float2 sc = ((const float2*)table)[pos*64 + l];
  float o1 = (v1*sc.y - v2*sc.x)*mult;
  float o2 = (v2*sc.y + v1*sc.x)*mult;
  u16* d = dst + (((size_t)((b<<nhl2) + n))*2048 + t)*128;
  d[l] = f2b(o1); d[64+l] = f2b(o2);
}

// ---------------- V transpose: vt[(b*8+kv)*128 + d][s] = qkv[b*T+s][3072+kv*128+d] ----------------
__global__ __launch_bounds__(256) void vtr(const u16* __restrict__ qkv, u16* __restrict__ vt){
  __shared__ float t[64][65];
  int bk = blockIdx.z;              // b*8+kv
  int t0 = blockIdx.y*64, d0 = blockIdx.x*64;
  int b = bk>>3, kv = bk&7;
  int tid = threadIdx.x;
  #pragma unroll
  for (int p=0;p<16;p++){ int e = p*256+tid; int r = e>>6, c = e&63;
    t[r][c] = b2f(qkv[(size_t)(b*2048 + t0 + r)*4096 + 3072 + kv*128 + d0 + c]); }
  __syncthreads();
  #pragma unroll
  for (int p=0;p<16;p++){ int e = p*256+tid; int c = e>>6, r = e&63;
    vt[((size_t)bk*128 + d0 + c)*2048 + t0 + r] = f2b(t[r][c]); }
}

// ---------------- flash attention, causal, GQA g=2 ----------------
// Pair-folded for balance: block pair p handles q-tile p (p+1 KV tiles) then
// q-tile 31-p (32-p KV tiles) -> exactly 33 tiles per block. Double-buffered
// KV staging, one barrier per tile. 512 blocks x 4 waves, 2 blocks/CU (72KB LDS).
__global__ __launch_bounds__(256,2) void attn_kern(const u16* __restrict__ qn, const u16* __restrict__ kn,
                                                   const u16* __restrict__ vt, u16* __restrict__ enc){
  __shared__ u16 Ks[2][64*128];   // [s][d], swizzled
  __shared__ u16 Vs[2][64*128];   // [d][s], swizzled
  __shared__ u16 Ps[4*16*64];     // per-wave P, swizzled
  const int idx = blockIdx.x;
  const int pp = idx>>5;               // pair 0..15
  const int hb = idx & 31;
  const int hn = hb & 15, b = hb >> 4;
  const int kv = hn>>1;
  const int tid = threadIdx.x, w = tid>>6, l = tid&63;
  const int l15 = l&15, lg = l>>4;
  const u16* qh = qn + ((size_t)(b*16+hn))*2048*128;
  const u16* kh = kn + ((size_t)(b*8+kv))*2048*128;
  const u16* vh = vt + ((size_t)(b*8+kv))*128*2048;
  const int qbA = pp, qbB = 31-pp;

  int qr0 = qbA*64 + w*16;
  s16x8 qf[4];
  #pragma unroll
  for (int kb=0;kb<4;kb++)
    qf[kb] = *(const s16x8*)(qh + (size_t)(qr0 + l15)*128 + kb*32 + lg*8);

  const f32x4 z4 = {0.f,0.f,0.f,0.f};
  f32x4 o[8];
  #pragma unroll
  for (int dn=0;dn<8;dn++) o[dn] = z4;
  float mrow[4], lp[4];
  #pragma unroll
  for (int r=0;r<4;r++){ mrow[r] = KMASKF; lp[r] = 0.f; }

  const char* KsB0 = (const char*)&Ks[0][0];
  const char* VsB0 = (const char*)&Vs[0][0];
  char* PsB = (char*)Ps + w*2048;

  auto stage = [&](int s0, int bi){
    #pragma unroll
    for (int i=0;i<4;i++){
      int slot = (w*4+i)*64 + l;
      { int row = slot>>4, g = slot&15, gl = g ^ (row&7);
        glds16(kh + (size_t)(s0+row)*128 + gl*8, &Ks[bi][0] + slot*8); }
      { int row = slot>>3, g = slot&7, gl = g ^ (row&7);
        glds16(vh + (size_t)row*2048 + s0 + gl*8, &Vs[bi][0] + slot*8); }
    }
  };

  auto epilogue = [&](int qr){
    #pragma unroll
    for (int r=0;r<4;r++){
      float s = lp[r];
      s += __shfl_xor(s,1); s += __shfl_xor(s,2); s += __shfl_xor(s,4); s += __shfl_xor(s,8);
      lp[r] = 1.f/s;
    }
    #pragma unroll
    for (int dn=0;dn<8;dn++)
      #pragma unroll
      for (int r=0;r<4;r++){
        size_t row = (size_t)b*2048 + qr + lg*4 + r;
        size_t col = hn*128 + dn*16 + l15;
        enc[row*2048 + col] = f2b(o[dn][r]*lp[r]);
      }
  };

  stage(0, 0);
  __syncthreads();

  int cur = 0;
  for (int it=0; it<=32; ++it){
    if (it < 32){
      int s0n = (it+1 <= pp) ? (it+1)*64 : (it-pp)*64;
      stage(s0n, cur^1);
    }
    const int s0 = (it <= pp) ? it*64 : (it-pp-1)*64;
    const char* KsB = KsB0 + cur*16384;
    const char* VsB = VsB0 + cur*16384;

    f32x4 sa[4];
    #pragma unroll
    for (int nc=0;nc<4;nc++) sa[nc] = z4;
    #pragma unroll
    for (int kb=0;kb<4;kb++){
      s16x8 kf[4];
      #pragma unroll
      for (int nc=0;nc<4;nc++){
        int srow = nc*16 + l15;
        int cb = (kb*64 + lg*16) ^ ((srow&7)<<4);
        kf[nc] = *(const s16x8*)(KsB + srow*256 + cb);
      }
      #pragma unroll
      for (int nc=0;nc<4;nc++)
        sa[nc] = mfma16(qf[kb], kf[nc], sa[nc]);
    }
    if (it == pp || it == 32){
      #pragma unroll
      for (int nc=0;nc<4;nc++)
        #pragma unroll
        for (int r=0;r<4;r++){
          int row = qr0 + lg*4 + r;
          int col = s0 + nc*16 + l15;
          if (col > row) sa[nc][r] = KMASKF;
        }
    }
    #pragma unroll
    for (int r=0;r<4;r++){
      float pm = fmaxf(fmaxf(sa[0][r], sa[1][r]), fmaxf(sa[2][r], sa[3][r]));
      pm = fmaxf(pm, __shfl_xor(pm,1));
      pm = fmaxf(pm, __shfl_xor(pm,2));
      pm = fmaxf(pm, __shfl_xor(pm,4));
      pm = fmaxf(pm, __shfl_xor(pm,8));
      float mo = mrow[r];
      float mn = fmaxf(mo, pm);
      float sc = __expf(mo - mn);
      mrow[r] = mn;
      int rowp = lg*4 + r;
      float ls = 0.f;
      #pragma unroll
      for (int nc=0;nc<4;nc++){
        float p = __expf(sa[nc][r] - mn);
        ls += p;
        int cb = ((nc*16 + l15)*2) ^ ((rowp&7)<<4);
        *(u16*)(PsB + rowp*128 + cb) = f2b(p);
      }
      lp[r] = lp[r]*sc + ls;
      #pragma unroll
      for (int dn=0;dn<8;dn++) o[dn][r] *= sc;
    }
    asm volatile("" ::: "memory");   // order P ds_writes before PV ds_reads (same wave)
    #pragma unroll
    for (int kb=0;kb<2;kb++){
      int rowp = l15;
      int cbp = (kb*64 + lg*16) ^ ((rowp&7)<<4);
      s16x8 pf = *(const s16x8*)(PsB + rowp*128 + cbp);
      #pragma unroll
      for (int dn=0;dn<8;dn++){
        int vrow = dn*16 + l15;
        int cb = (kb*64 + lg*16) ^ ((vrow&7)<<4);
        s16x8 vf = *(const s16x8*)(VsB + vrow*128 + cb);
        o[dn] = mfma16(pf, vf, o[dn]);
      }
    }
    if (it == pp){
      // finish q-tile A: write it out, reset state, switch to q-tile B
      epilogue(qr0);
      qr0 = qbB*64 + w*16;
      #pragma unroll
      for (int kb=0;kb<4;kb++)
        qf[kb] = *(const s16x8*)(qh + (size_t)(qr0 + l15)*128 + kb*32 + lg*8);
      #pragma unroll
      for (int dn=0;dn<8;dn++) o[dn] = z4;
      #pragma unroll
      for (int r=0;r<4;r++){ mrow[r] = KMASKF; lp[r] = 0.f; }
    }
    __syncthreads();
    cur ^= 1;
  }
  epilogue(qr0);
}

extern "C" void kernel_launch(void* const* d_in, const int* in_sizes, int n_in,
                              void* d_out, int out_size, void* d_ws, size_t ws_size,
                              hipStream_t stream){
  const float* x      = (const float*)d_in[0];
  const int*   segpos = (const int*)d_in[1];
  // d_in[2] = attn_mask: structurally causal (tril) — handled analytically in attn_kern
  const float* qw     = (const float*)d_in[3];
  const float* kvw    = (const float*)d_in[4];
  const float* ow     = (const float*)d_in[5];
  const float* qs     = (const float*)d_in[6];
  const float* ks     = (const float*)d_in[7];
  float* out = (float*)d_out;

  char* ws = (char*)d_ws;
  size_t off = 0;
  auto alloc = [&](size_t bytes)->void*{ void* p = ws + off; off += (bytes + 255) & ~(size_t)255; return p; };
  u16*   xb    = (u16*)alloc((size_t)4096*2048*2);    // x bf16
  u16*   wqkvt = (u16*)alloc((size_t)4096*2048*2);    // combined qkv weight, B^T
  u16*   wot   = (u16*)alloc((size_t)2048*2048*2);    // o_w^T
  u16*   qkv   = (u16*)alloc((size_t)4096*4096*2);    // qkv projections bf16
  u16*   qn    = (u16*)alloc((size_t)2*16*2048*128*2);// normed+roped q (SCALAR folded)
  u16*   kn    = (u16*)alloc((size_t)2*8*2048*128*2); // normed+roped k
  u16*   vt    = (u16*)alloc((size_t)2*8*128*2048*2); // v transposed [d][s]
  u16*   enc   = (u16*)alloc((size_t)4096*2048*2);    // attention output bf16
  float* table = (float*)alloc((size_t)2048*64*2*4);  // rope sin/cos

  cvt_f32_bf16<<<4096,256,0,stream>>>(x, xb);
  build_wqkvt<<<dim3(2,32,32),256,0,stream>>>(qw, kvw, wqkvt);
  tr2048<<<dim3(32,32),256,0,stream>>>(ow, wot);
  rope_table<<<512,256,0,stream>>>(table);
  gemm_bt<true><<<dim3(32,32),256,0,stream>>>(xb, wqkvt, qkv, 2048, 4096);     // bf16 out
  norm_rope<<<16384,256,0,stream>>>(qkv, table, qs, segpos, qn, 4, 0,    SCALAR_F);
  norm_rope<<<8192, 256,0,stream>>>(qkv, table, ks, segpos, kn, 3, 2048, 1.0f);
  vtr<<<dim3(2,32,16),256,0,stream>>>(qkv, vt);
  attn_kern<<<512,256,0,stream>>>(qn, kn, vt, enc);
  gemm_bt<false><<<dim3(16,32),256,0,stream>>>(enc, wot, out, 2048, 2048);     // f32 out
}

// Round 4
// 380.623 us; speedup vs baseline: 1.3845x; 1.0106x over previous
//
#include <hip/hip_runtime.h>

typedef unsigned short u16;
typedef __attribute__((ext_vector_type(4))) float f32x4;
typedef __attribute__((ext_vector_type(8))) short s16x8;

#define SCALAR_F 0.08838834764831845f
#define KMASKF (-1e30f)

__device__ __forceinline__ u16 f2b(float f){
  unsigned u = __float_as_uint(f);
  unsigned r = u + 0x7FFFu + ((u>>16)&1u);
  return (u16)(r>>16);
}
__device__ __forceinline__ float b2f(u16 h){ return __uint_as_float(((unsigned)h)<<16); }

__device__ __forceinline__ f32x4 mfma16(s16x8 a, s16x8 b, f32x4 c){
  return __builtin_amdgcn_mfma_f32_16x16x32_bf16(a, b, c, 0, 0, 0);
}

__device__ __forceinline__ void glds16(const u16* g, u16* l){
  __builtin_amdgcn_global_load_lds((const __attribute__((address_space(1))) unsigned*)g,
                                   (__attribute__((address_space(3))) unsigned*)l, 16, 0, 0);
}

// ---------------- x f32 -> bf16 ----------------
__global__ __launch_bounds__(256) void cvt_f32_bf16(const float* __restrict__ in, u16* __restrict__ out){
  int i = blockIdx.x*256 + threadIdx.x;
  const float4* p = (const float4*)in;
  float4 a = p[2*i], b = p[2*i+1];
  s16x8 r;
  r[0]=(short)f2b(a.x); r[1]=(short)f2b(a.y); r[2]=(short)f2b(a.z); r[3]=(short)f2b(a.w);
  r[4]=(short)f2b(b.x); r[5]=(short)f2b(b.y); r[6]=(short)f2b(b.z); r[7]=(short)f2b(b.w);
  *(s16x8*)(out + (size_t)i*8) = r;
}

// ---------------- build combined qkv weight, B^T layout: wt[c][d], c in [0,4096) ----------------
__global__ __launch_bounds__(256) void build_wqkvt(const float* __restrict__ qw, const float* __restrict__ kvw,
                                                   u16* __restrict__ out){
  __shared__ float t[64][65];
  int head = blockIdx.z;            // 0..31: 16 q heads, 8 k heads, 8 v heads
  int d0 = blockIdx.y*64, h0 = blockIdx.x*64;
  const float* src; int colbase;
  if (head < 16){ src = qw + (size_t)head*2048*128; colbase = head*128; }
  else if (head < 24){ int k = head-16; src = kvw + (size_t)k*2048*128; colbase = 2048 + k*128; }
  else { int k = head-24; src = kvw + (size_t)(8+k)*2048*128; colbase = 3072 + k*128; }
  int tid = threadIdx.x;
  #pragma unroll
  for (int p=0;p<16;p++){ int e = p*256+tid; int r = e>>6, c = e&63;
    t[r][c] = src[(size_t)(d0+r)*128 + h0 + c]; }
  __syncthreads();
  #pragma unroll
  for (int p=0;p<16;p++){ int e = p*256+tid; int c = e>>6, r = e&63;
    out[(size_t)(colbase + h0 + c)*2048 + d0 + r] = f2b(t[r][c]); }
}

// ---------------- transpose o_w (2048x2048 f32) -> bf16 B^T ----------------
__global__ __launch_bounds__(256) void tr2048(const float* __restrict__ src, u16* __restrict__ out){
  __shared__ float t[64][65];
  int r0 = blockIdx.y*64, c0 = blockIdx.x*64;
  int tid = threadIdx.x;
  #pragma unroll
  for (int p=0;p<16;p++){ int e = p*256+tid; int r = e>>6, c = e&63;
    t[r][c] = src[(size_t)(r0+r)*2048 + c0 + c]; }
  __syncthreads();
  #pragma unroll
  for (int p=0;p<16;p++){ int e = p*256+tid; int c = e>>6, r = e&63;
    out[(size_t)(c0+c)*2048 + r0 + r] = f2b(t[r][c]); }
}

// ---------------- RoPE sin/cos table: table[pos][i] = (sin, cos) ----------------
__global__ __launch_bounds__(256) void rope_table(float* __restrict__ table){
  int tid = blockIdx.x*256 + threadIdx.x;     // 2048*64
  int pos = tid>>6, i = tid&63;
  float ts = powf(10000.f, (float)i * (1.f/64.f));
  float ang = (float)pos / ts;
  ((float2*)table)[tid] = make_float2(sinf(ang), cosf(ang));
}

// ---------------- 256x256-tile GEMM, 8 waves, BK=32, 4-deep counted-vmcnt pipeline ----------------
// C[M,N] = A[M,K] * Bt[N,K]^T, bf16 in, bf16 out. Grid must be (M/256)*(N/256) with N/256==16.
// LDS 128KB -> 1 block/CU. Race-free: iteration t stages tile t+3 into buffer (t+3)&3,
// whose last reader (compute(t-1)) finished before the previous barrier. vmcnt(8) keeps
// 2 tiles (8 loads) in flight across barriers (T3+T4); raw s_barrier avoids the implicit
// vmcnt(0) drain __syncthreads() would emit.
__global__ __launch_bounds__(512,2) void gemm256(const u16* __restrict__ A, const u16* __restrict__ Bt,
                                                 u16* __restrict__ C, int K, int ldc){
  __shared__ u16 Asw[4][256*32];
  __shared__ u16 Bsw[4][256*32];
  const int tid = threadIdx.x;
  const int wid = tid>>6, l = tid&63;
  const int wr = wid>>2, wc = wid&3;         // 2 x 4 wave grid
  const int l15 = l&15, lg = l>>4;
  const int wg = blockIdx.x;
  const int swz = (wg&7)*32 + (wg>>3);       // XCD-chunked: each XCD owns 2 full bm-rows
  const size_t m0 = (size_t)(swz>>4)*256, n0 = (size_t)(swz&15)*256;

  const f32x4 z4 = {0.f,0.f,0.f,0.f};
  f32x4 acc[8][4];
  #pragma unroll
  for (int mi=0;mi<8;mi++)
    #pragma unroll
    for (int ni=0;ni<4;ni++) acc[mi][ni] = z4;

  // stage tile (rows 0..255, k0..k0+31) into buffer bi. Linear LDS dest (lane*16B),
  // inverse-swizzled global source: granule g -> row g>>2, src col-granule (g&3)^((g>>3)&3).
  auto stage = [&](int k0, int bi){
    #pragma unroll
    for (int c=0;c<2;c++){
      int g = c*512 + tid;
      int row = g>>2;
      int sc = (g&3) ^ ((g>>3)&3);
      glds16(A  + (m0+row)*K + k0 + sc*8, &Asw[bi][0] + g*8);
      glds16(Bt + (n0+row)*K + k0 + sc*8, &Bsw[bi][0] + g*8);
    }
  };

  // fragment read: logical (row r, k-granule lg) at physical byte r*64 + 16*(lg ^ ((r>>1)&3))
  auto compute = [&](int bi){
    const char* AsB = (const char*)&Asw[bi][0];
    const char* BsB = (const char*)&Bsw[bi][0];
    s16x8 bfr[4];
    #pragma unroll
    for (int ni=0;ni<4;ni++){
      int r = wc*64 + ni*16 + l15;
      bfr[ni] = *(const s16x8*)(BsB + r*64 + ((lg*16) ^ (((r>>1)&3)<<4)));
    }
    __builtin_amdgcn_s_setprio(1);
    #pragma unroll
    for (int mi=0;mi<8;mi++){
      int r = wr*128 + mi*16 + l15;
      s16x8 af = *(const s16x8*)(AsB + r*64 + ((lg*16) ^ (((r>>1)&3)<<4)));
      #pragma unroll
      for (int ni=0;ni<4;ni++)
        acc[mi][ni] = mfma16(af, bfr[ni], acc[mi][ni]);
    }
    __builtin_amdgcn_s_setprio(0);
  };

  const int NT = K>>5;
  stage(0,0); stage(32,1); stage(64,2);
  asm volatile("s_waitcnt vmcnt(8)" ::: "memory");   // tile 0 resident; tiles 1,2 in flight
  __builtin_amdgcn_s_barrier();
  for (int t=0; t<NT; ++t){
    if (t+3 < NT) stage((t+3)<<5, (t+3)&3);
    compute(t&3);
    int rem = NT-1-t;
    if (rem >= 3)      { asm volatile("s_waitcnt vmcnt(8)" ::: "memory"); }
    else if (rem == 2) { asm volatile("s_waitcnt vmcnt(4)" ::: "memory"); }
    else if (rem == 1) { asm volatile("s_waitcnt vmcnt(0)" ::: "memory"); }
    __builtin_amdgcn_s_barrier();
  }

  #pragma unroll
  for (int mi=0;mi<8;mi++)
    #pragma unroll
    for (int ni=0;ni<4;ni++)
      #pragma unroll
      for (int r=0;r<4;r++){
        size_t row = m0 + wr*128 + mi*16 + lg*4 + r;
        size_t col = n0 + wc*64 + ni*16 + l15;
        C[row*ldc + col] = f2b(acc[mi][ni][r]);
      }
}

// ---------------- GEMM: C[M,N] = A[M,K] * Bt[N,K]^T, bf16 in, f32 acc ----------------
template<bool OUTBF16>
__global__ __launch_bounds__(256) void gemm_bt(const u16* __restrict__ A, const u16* __restrict__ Bt,
                                               void* __restrict__ C, int K, int ldc){
  __shared__ u16 As[128*64];
  __shared__ u16 Bs[128*64];
  const int tid = threadIdx.x, w = tid>>6, l = tid&63;
  const int wm = w>>1, wn = w&1;
  const int l15 = l&15, lg = l>>4, l7 = l&7;
  const size_t m0 = (size_t)blockIdx.y*128, n0 = (size_t)blockIdx.x*128;
  const f32x4 z4 = {0.f,0.f,0.f,0.f};
  f32x4 acc[4][4];
  #pragma unroll
  for (int m=0;m<4;m++)
    #pragma unroll
    for (int n=0;n<4;n++) acc[m][n] = z4;
  const char* AsB = (const char*)As; const char* BsB = (const char*)Bs;
  int colsw[2];
  colsw[0] = (lg*16) ^ (l7<<4);
  colsw[1] = (64 + lg*16) ^ (l7<<4);
  int arow[4], brow[4];
  #pragma unroll
  for (int m=0;m<4;m++){ arow[m] = (wm*64 + m*16 + l15)*128; brow[m] = (wn*64 + m*16 + l15)*128; }
  const int sgl = l7 ^ (l>>3);  // staging pre-swizzled granule
  for (int k0=0;k0<K;k0+=64){
    #pragma unroll
    for (int i=0;i<4;i++){
      int slot = (w*4+i)*64 + l;
      int row = slot>>3;
      glds16(A  + (m0+row)*K + k0 + sgl*8, (u16*)As + slot*8);
      glds16(Bt + (n0+row)*K + k0 + sgl*8, (u16*)Bs + slot*8);
    }
    __syncthreads();
    #pragma unroll
    for (int kb=0;kb<2;kb++){
      s16x8 af[4], bf[4];
      #pragma unroll
      for (int m=0;m<4;m++) af[m] = *(const s16x8*)(AsB + arow[m] + colsw[kb]);
      #pragma unroll
      for (int n=0;n<4;n++) bf[n] = *(const s16x8*)(BsB + brow[n] + colsw[kb]);
      #pragma unroll
      for (int m=0;m<4;m++)
        #pragma unroll
        for (int n=0;n<4;n++)
          acc[m][n] = mfma16(af[m], bf[n], acc[m][n]);
    }
    __syncthreads();
  }
  #pragma unroll
  for (int m=0;m<4;m++)
    #pragma unroll
    for (int n=0;n<4;n++)
      #pragma unroll
      for (int r=0;r<4;r++){
        size_t row = m0 + wm*64 + m*16 + lg*4 + r;
        size_t col = n0 + wn*64 + n*16 + l15;
        if (OUTBF16) ((u16*)C)[row*ldc + col] = f2b(acc[m][n][r]);
        else ((float*)C)[row*ldc + col] = acc[m][n][r];
      }
}

// ---------------- fused RMSNorm + RoPE (+SCALAR for q) ----------------
// one wave per (b,t,head) row; lane l holds elems (l, l+64)
__global__ __launch_bounds__(256) void norm_rope(const u16* __restrict__ qkv, const float* __restrict__ table,
                                                 const float* __restrict__ scale, const int* __restrict__ segpos,
                                                 u16* __restrict__ dst, int nhl2, int colbase, float mult){
  int w = threadIdx.x>>6, l = threadIdx.x&63;
  int rid = blockIdx.x*4 + w;
  int bt = rid >> nhl2;
  int n  = rid & ((1<<nhl2)-1);
  int b = bt >> 11, t = bt & 2047;
  const u16* src = qkv + (size_t)bt*4096 + colbase + n*128;
  float x1 = b2f(src[l]), x2 = b2f(src[64+l]);
  float ss = x1*x1 + x2*x2;
  #pragma unroll
  for (int off=32; off; off>>=1) ss += __shfl_xor(ss, off);
  float rs = rsqrtf(ss*(1.f/128.f) + 1e-6f);
  float v1 = x1*rs*scale[l], v2 = x2*rs*scale[64+l];
  int pos = segpos[bt];
  float2 sc = ((const float2*)table)[pos*64 + l];
  float o1 = (v1*sc.y - v2*sc.x)*mult;
  float o2 = (v2*sc.y + v1*sc.x)*mult;
  u16* d = dst + (((size_t)((b<<nhl2) + n))*2048 + t)*128;
  d[l] = f2b(o1); d[64+l] = f2b(o2);
}

// ---------------- V transpose: vt[(b*8+kv)*128 + d][s] = qkv[b*T+s][3072+kv*128+d] ----------------
__global__ __launch_bounds__(256) void vtr(const u16* __restrict__ qkv, u16* __restrict__ vt){
  __shared__ float t[64][65];
  int bk = blockIdx.z;              // b*8+kv
  int t0 = blockIdx.y*64, d0 = blockIdx.x*64;
  int b = bk>>3, kv = bk&7;
  int tid = threadIdx.x;
  #pragma unroll
  for (int p=0;p<16;p++){ int e = p*256+tid; int r = e>>6, c = e&63;
    t[r][c] = b2f(qkv[(size_t)(b*2048 + t0 + r)*4096 + 3072 + kv*128 + d0 + c]); }
  __syncthreads();
  #pragma unroll
  for (int p=0;p<16;p++){ int e = p*256+tid; int c = e>>6, r = e&63;
    vt[((size_t)bk*128 + d0 + c)*2048 + t0 + r] = f2b(t[r][c]); }
}

// ---------------- flash attention, causal, GQA g=2 ----------------
// Pair-folded for balance: block pair p handles q-tile p (p+1 KV tiles) then
// q-tile 31-p (32-p KV tiles) -> exactly 33 tiles per block. Double-buffered
// KV staging, one barrier per tile. 512 blocks x 4 waves, 2 blocks/CU (72KB LDS).
__global__ __launch_bounds__(256,2) void attn_kern(const u16* __restrict__ qn, const u16* __restrict__ kn,
                                                   const u16* __restrict__ vt, u16* __restrict__ enc){
  __shared__ u16 Ks[2][64*128];   // [s][d], swizzled
  __shared__ u16 Vs[2][64*128];   // [d][s], swizzled
  __shared__ u16 Ps[4*16*64];     // per-wave P, swizzled
  const int idx = blockIdx.x;
  const int pp = idx>>5;               // pair 0..15
  const int hb = idx & 31;
  const int hn = hb & 15, b = hb >> 4;
  const int kv = hn>>1;
  const int tid = threadIdx.x, w = tid>>6, l = tid&63;
  const int l15 = l&15, lg = l>>4;
  const u16* qh = qn + ((size_t)(b*16+hn))*2048*128;
  const u16* kh = kn + ((size_t)(b*8+kv))*2048*128;
  const u16* vh = vt + ((size_t)(b*8+kv))*128*2048;
  const int qbA = pp, qbB = 31-pp;

  int qr0 = qbA*64 + w*16;
  s16x8 qf[4];
  #pragma unroll
  for (int kb=0;kb<4;kb++)
    qf[kb] = *(const s16x8*)(qh + (size_t)(qr0 + l15)*128 + kb*32 + lg*8);

  const f32x4 z4 = {0.f,0.f,0.f,0.f};
  f32x4 o[8];
  #pragma unroll
  for (int dn=0;dn<8;dn++) o[dn] = z4;
  float mrow[4], lp[4];
  #pragma unroll
  for (int r=0;r<4;r++){ mrow[r] = KMASKF; lp[r] = 0.f; }

  const char* KsB0 = (const char*)&Ks[0][0];
  const char* VsB0 = (const char*)&Vs[0][0];
  char* PsB = (char*)Ps + w*2048;

  auto stage = [&](int s0, int bi){
    #pragma unroll
    for (int i=0;i<4;i++){
      int slot = (w*4+i)*64 + l;
      { int row = slot>>4, g = slot&15, gl = g ^ (row&7);
        glds16(kh + (size_t)(s0+row)*128 + gl*8, &Ks[bi][0] + slot*8); }
      { int row = slot>>3, g = slot&7, gl = g ^ (row&7);
        glds16(vh + (size_t)row*2048 + s0 + gl*8, &Vs[bi][0] + slot*8); }
    }
  };

  auto epilogue = [&](int qr){
    #pragma unroll
    for (int r=0;r<4;r++){
      float s = lp[r];
      s += __shfl_xor(s,1); s += __shfl_xor(s,2); s += __shfl_xor(s,4); s += __shfl_xor(s,8);
      lp[r] = 1.f/s;
    }
    #pragma unroll
    for (int dn=0;dn<8;dn++)
      #pragma unroll
      for (int r=0;r<4;r++){
        size_t row = (size_t)b*2048 + qr + lg*4 + r;
        size_t col = hn*128 + dn*16 + l15;
        enc[row*2048 + col] = f2b(o[dn][r]*lp[r]);
      }
  };

  stage(0, 0);
  __syncthreads();

  int cur = 0;
  for (int it=0; it<=32; ++it){
    if (it < 32){
      int s0n = (it+1 <= pp) ? (it+1)*64 : (it-pp)*64;
      stage(s0n, cur^1);
    }
    const int s0 = (it <= pp) ? it*64 : (it-pp-1)*64;
    const char* KsB = KsB0 + cur*16384;
    const char* VsB = VsB0 + cur*16384;

    f32x4 sa[4];
    #pragma unroll
    for (int nc=0;nc<4;nc++) sa[nc] = z4;
    #pragma unroll
    for (int kb=0;kb<4;kb++){
      s16x8 kf[4];
      #pragma unroll
      for (int nc=0;nc<4;nc++){
        int srow = nc*16 + l15;
        int cb = (kb*64 + lg*16) ^ ((srow&7)<<4);
        kf[nc] = *(const s16x8*)(KsB + srow*256 + cb);
      }
      #pragma unroll
      for (int nc=0;nc<4;nc++)
        sa[nc] = mfma16(qf[kb], kf[nc], sa[nc]);
    }
    if (it == pp || it == 32){
      #pragma unroll
      for (int nc=0;nc<4;nc++)
        #pragma unroll
        for (int r=0;r<4;r++){
          int row = qr0 + lg*4 + r;
          int col = s0 + nc*16 + l15;
          if (col > row) sa[nc][r] = KMASKF;
        }
    }
    #pragma unroll
    for (int r=0;r<4;r++){
      float pm = fmaxf(fmaxf(sa[0][r], sa[1][r]), fmaxf(sa[2][r], sa[3][r]));
      pm = fmaxf(pm, __shfl_xor(pm,1));
      pm = fmaxf(pm, __shfl_xor(pm,2));
      pm = fmaxf(pm, __shfl_xor(pm,4));
      pm = fmaxf(pm, __shfl_xor(pm,8));
      float mo = mrow[r];
      float mn = fmaxf(mo, pm);
      float sc = __expf(mo - mn);
      mrow[r] = mn;
      int rowp = lg*4 + r;
      float ls = 0.f;
      #pragma unroll
      for (int nc=0;nc<4;nc++){
        float p = __expf(sa[nc][r] - mn);
        ls += p;
        int cb = ((nc*16 + l15)*2) ^ ((rowp&7)<<4);
        *(u16*)(PsB + rowp*128 + cb) = f2b(p);
      }
      lp[r] = lp[r]*sc + ls;
      #pragma unroll
      for (int dn=0;dn<8;dn++) o[dn][r] *= sc;
    }
    asm volatile("" ::: "memory");   // order P ds_writes before PV ds_reads (same wave)
    #pragma unroll
    for (int kb=0;kb<2;kb++){
      int rowp = l15;
      int cbp = (kb*64 + lg*16) ^ ((rowp&7)<<4);
      s16x8 pf = *(const s16x8*)(PsB + rowp*128 + cbp);
      #pragma unroll
      for (int dn=0;dn<8;dn++){
        int vrow = dn*16 + l15;
        int cb = (kb*64 + lg*16) ^ ((vrow&7)<<4);
        s16x8 vf = *(const s16x8*)(VsB + vrow*128 + cb);
        o[dn] = mfma16(pf, vf, o[dn]);
      }
    }
    if (it == pp){
      // finish q-tile A: write it out, reset state, switch to q-tile B
      epilogue(qr0);
      qr0 = qbB*64 + w*16;
      #pragma unroll
      for (int kb=0;kb<4;kb++)
        qf[kb] = *(const s16x8*)(qh + (size_t)(qr0 + l15)*128 + kb*32 + lg*8);
      #pragma unroll
      for (int dn=0;dn<8;dn++) o[dn] = z4;
      #pragma unroll
      for (int r=0;r<4;r++){ mrow[r] = KMASKF; lp[r] = 0.f; }
    }
    __syncthreads();
    cur ^= 1;
  }
  epilogue(qr0);
}

extern "C" void kernel_launch(void* const* d_in, const int* in_sizes, int n_in,
                              void* d_out, int out_size, void* d_ws, size_t ws_size,
                              hipStream_t stream){
  const float* x      = (const float*)d_in[0];
  const int*   segpos = (const int*)d_in[1];
  // d_in[2] = attn_mask: structurally causal (tril) — handled analytically in attn_kern
  const float* qw     = (const float*)d_in[3];
  const float* kvw    = (const float*)d_in[4];
  const float* ow     = (const float*)d_in[5];
  const float* qs     = (const float*)d_in[6];
  const float* ks     = (const float*)d_in[7];
  float* out = (float*)d_out;

  char* ws = (char*)d_ws;
  size_t off = 0;
  auto alloc = [&](size_t bytes)->void*{ void* p = ws + off; off += (bytes + 255) & ~(size_t)255; return p; };
  u16*   xb    = (u16*)alloc((size_t)4096*2048*2);    // x bf16
  u16*   wqkvt = (u16*)alloc((size_t)4096*2048*2);    // combined qkv weight, B^T
  u16*   wot   = (u16*)alloc((size_t)2048*2048*2);    // o_w^T
  u16*   qkv   = (u16*)alloc((size_t)4096*4096*2);    // qkv projections bf16
  u16*   qn    = (u16*)alloc((size_t)2*16*2048*128*2);// normed+roped q (SCALAR folded)
  u16*   kn    = (u16*)alloc((size_t)2*8*2048*128*2); // normed+roped k
  u16*   vt    = (u16*)alloc((size_t)2*8*128*2048*2); // v transposed [d][s]
  u16*   enc   = (u16*)alloc((size_t)4096*2048*2);    // attention output bf16
  float* table = (float*)alloc((size_t)2048*64*2*4);  // rope sin/cos

  cvt_f32_bf16<<<4096,256,0,stream>>>(x, xb);
  build_wqkvt<<<dim3(2,32,32),256,0,stream>>>(qw, kvw, wqkvt);
  tr2048<<<dim3(32,32),256,0,stream>>>(ow, wot);
  rope_table<<<512,256,0,stream>>>(table);
  gemm256<<<256,512,0,stream>>>(xb, wqkvt, qkv, 2048, 4096);                   // qkv proj, bf16 out
  norm_rope<<<16384,256,0,stream>>>(qkv, table, qs, segpos, qn, 4, 0,    SCALAR_F);
  norm_rope<<<8192, 256,0,stream>>>(qkv, table, ks, segpos, kn, 3, 2048, 1.0f);
  vtr<<<dim3(2,32,16),256,0,stream>>>(qkv, vt);
  attn_kern<<<512,256,0,stream>>>(qn, kn, vt, enc);
  gemm_bt<false><<<dim3(16,32),256,0,stream>>>(enc, wot, out, 2048, 2048);     // f32 out
}

// Round 6
// 358.577 us; speedup vs baseline: 1.4696x; 1.0615x over previous
//
#include <hip/hip_runtime.h>

typedef unsigned short u16;
typedef __attribute__((ext_vector_type(4))) float f32x4;
typedef __attribute__((ext_vector_type(8))) short s16x8;

#define SCALAR_F 0.08838834764831845f
#define KMASKF (-1e30f)

__device__ __forceinline__ u16 f2b(float f){
  unsigned u = __float_as_uint(f);
  unsigned r = u + 0x7FFFu + ((u>>16)&1u);
  return (u16)(r>>16);
}
__device__ __forceinline__ float b2f(u16 h){ return __uint_as_float(((unsigned)h)<<16); }

__device__ __forceinline__ f32x4 mfma16(s16x8 a, s16x8 b, f32x4 c){
  return __builtin_amdgcn_mfma_f32_16x16x32_bf16(a, b, c, 0, 0, 0);
}

__device__ __forceinline__ void glds16(const u16* g, u16* l){
  __builtin_amdgcn_global_load_lds((const __attribute__((address_space(1))) unsigned*)g,
                                   (__attribute__((address_space(3))) unsigned*)l, 16, 0, 0);
}

#define PHASE_BAR() asm volatile("s_barrier" ::: "memory")
#define LGKM0()     do { asm volatile("s_waitcnt lgkmcnt(0)" ::: "memory"); __builtin_amdgcn_sched_barrier(0); } while(0)

// ---------------- x f32 -> bf16 ----------------
__global__ __launch_bounds__(256) void cvt_f32_bf16(const float* __restrict__ in, u16* __restrict__ out){
  int i = blockIdx.x*256 + threadIdx.x;
  const float4* p = (const float4*)in;
  float4 a = p[2*i], b = p[2*i+1];
  s16x8 r;
  r[0]=(short)f2b(a.x); r[1]=(short)f2b(a.y); r[2]=(short)f2b(a.z); r[3]=(short)f2b(a.w);
  r[4]=(short)f2b(b.x); r[5]=(short)f2b(b.y); r[6]=(short)f2b(b.z); r[7]=(short)f2b(b.w);
  *(s16x8*)(out + (size_t)i*8) = r;
}

// ---------------- build combined qkv weight, B^T layout: wt[c][d], c in [0,4096) ----------------
__global__ __launch_bounds__(256) void build_wqkvt(const float* __restrict__ qw, const float* __restrict__ kvw,
                                                   u16* __restrict__ out){
  __shared__ float t[64][65];
  int head = blockIdx.z;            // 0..31: 16 q heads, 8 k heads, 8 v heads
  int d0 = blockIdx.y*64, h0 = blockIdx.x*64;
  const float* src; int colbase;
  if (head < 16){ src = qw + (size_t)head*2048*128; colbase = head*128; }
  else if (head < 24){ int k = head-16; src = kvw + (size_t)k*2048*128; colbase = 2048 + k*128; }
  else { int k = head-24; src = kvw + (size_t)(8+k)*2048*128; colbase = 3072 + k*128; }
  int tid = threadIdx.x;
  #pragma unroll
  for (int p=0;p<16;p++){ int e = p*256+tid; int r = e>>6, c = e&63;
    t[r][c] = src[(size_t)(d0+r)*128 + h0 + c]; }
  __syncthreads();
  #pragma unroll
  for (int p=0;p<16;p++){ int e = p*256+tid; int c = e>>6, r = e&63;
    out[(size_t)(colbase + h0 + c)*2048 + d0 + r] = f2b(t[r][c]); }
}

// ---------------- transpose o_w (2048x2048 f32) -> bf16 B^T ----------------
__global__ __launch_bounds__(256) void tr2048(const float* __restrict__ src, u16* __restrict__ out){
  __shared__ float t[64][65];
  int r0 = blockIdx.y*64, c0 = blockIdx.x*64;
  int tid = threadIdx.x;
  #pragma unroll
  for (int p=0;p<16;p++){ int e = p*256+tid; int r = e>>6, c = e&63;
    t[r][c] = src[(size_t)(r0+r)*2048 + c0 + c]; }
  __syncthreads();
  #pragma unroll
  for (int p=0;p<16;p++){ int e = p*256+tid; int c = e>>6, r = e&63;
    out[(size_t)(c0+c)*2048 + r0 + r] = f2b(t[r][c]); }
}

// ---------------- RoPE sin/cos table: table[pos][i] = (sin, cos) ----------------
__global__ __launch_bounds__(256) void rope_table(float* __restrict__ table){
  int tid = blockIdx.x*256 + threadIdx.x;     // 2048*64
  int pos = tid>>6, i = tid&63;
  float ts = powf(10000.f, (float)i * (1.f/64.f));
  float ang = (float)pos / ts;
  ((float2*)table)[tid] = make_float2(sinf(ang), cosf(ang));
}

// ---------------- 256x256 GEMM, 8 waves, BK=64, 4-phase fine interleave (T2+T3+T4+T5) ----------------
// C[M,N] = A[M,K] * Bt[N,K]^T, bf16 in/out. Grid = (M/256)*16, N = 4096 fixed.
// LDS: 2 buf x {A0,A1,B0,B1} halves x 16KB = 128KB, 1 block/CU.
// Per K-tile, 4 phases: {ds_read frag subtile || stage 1-2 half-tiles -> s_barrier ->
// lgkmcnt(0) -> setprio(1) + 16 MFMA + setprio(0) -> s_barrier}. Counted vmcnt(4) once
// per tile at P4 (never 0 in main loop). All 24 frags (16 A + 8 B) held in registers.
// Race-freedom: B-halves of t+1 staged at P1/P2 (last read: P1/P2 of t-1, barrier-sep);
// A-halves of t+2 staged at P4 (A-frags of live buf register-resident after P3).
__global__ __launch_bounds__(512,2) void gemm256(const u16* __restrict__ A, const u16* __restrict__ Bt,
                                                 u16* __restrict__ C, int K, int ldc){
  __shared__ u16 Als[2][2][128*64];
  __shared__ u16 Bls[2][2][128*64];
  const int tid = threadIdx.x;
  const int wid = tid>>6, l = tid&63;
  const int wr = wid>>2, wc = wid&3;         // 2 x 4 wave grid
  const int l15 = l&15, lg = l>>4;
  const int wg = blockIdx.x;
  const int swz = (wg&7)*32 + (wg>>3);       // XCD-chunked swizzle (bijective for 256)
  const size_t m0 = (size_t)(swz>>4)*256, n0 = (size_t)(swz&15)*256;

  const f32x4 z4 = {0.f,0.f,0.f,0.f};
  f32x4 acc[8][4];
  #pragma unroll
  for (int mi=0;mi<8;mi++)
    #pragma unroll
    for (int ni=0;ni<4;ni++) acc[mi][ni] = z4;

  // stage one 128x64 half-tile (16KB) linearly; inverse-swizzled global source:
  // physical granule pg at row r holds logical granule pg^(r&7).
  auto stageA = [&](int k0, int bi, int h){
    #pragma unroll
    for (int c=0;c<2;c++){
      int g = c*512 + tid;
      int row = g>>3, pg = g&7;
      glds16(A + (m0 + h*128 + row)*K + k0 + ((pg ^ (row&7))<<3), &Als[bi][h][0] + g*8);
    }
  };
  auto stageB = [&](int k0, int bi, int h){
    #pragma unroll
    for (int c=0;c<2;c++){
      int g = c*512 + tid;
      int row = g>>3, pg = g&7;
      glds16(Bt + (n0 + h*128 + row)*K + k0 + ((pg ^ (row&7))<<3), &Bls[bi][h][0] + g*8);
    }
  };

  s16x8 af[8][2], bf[4][2];      // 16 + 8 frags, all held

  const int NT = K>>6;
  // prologue: tile0 fully, tile1 A-halves (B-halves of t+1 staged at P1/P2 of iter t)
  stageA(0,0,0); stageA(0,0,1); stageB(0,0,0); stageB(0,0,1);
  stageA(64,1,0); stageA(64,1,1);
  asm volatile("s_waitcnt vmcnt(4)" ::: "memory");
  PHASE_BAR();

  for (int t=0; t<NT; ++t){
    const int bi = t&1;
    const char* Ab = (const char*)&Als[bi][wr][0];
    const char* Bb = (const char*)&Bls[bi][wc>>1][0];
    const int brl = (wc&1)*64;               // local B row base within half
    const int kn1 = (t+1)<<6, kn2 = (t+2)<<6;

    // ---- P1: read A mi0-3 (8) + B ni0-1 (4); stage B0(t+1) ----
    #pragma unroll
    for (int mi=0;mi<4;mi++){
      int r = mi*16 + l15;
      #pragma unroll
      for (int kk=0;kk<2;kk++)
        af[mi][kk] = *(const s16x8*)(Ab + r*128 + (((kk*4+lg) ^ (r&7))<<4));
    }
    #pragma unroll
    for (int ni=0;ni<2;ni++){
      int r = brl + ni*16 + l15;
      #pragma unroll
      for (int kk=0;kk<2;kk++)
        bf[ni][kk] = *(const s16x8*)(Bb + r*128 + (((kk*4+lg) ^ (r&7))<<4));
    }
    if (t+1 < NT) stageB(kn1, bi^1, 0);
    PHASE_BAR(); LGKM0();
    __builtin_amdgcn_s_setprio(1);
    #pragma unroll
    for (int mi=0;mi<4;mi++)
      #pragma unroll
      for (int ni=0;ni<2;ni++)
        #pragma unroll
        for (int kk=0;kk<2;kk++)
          acc[mi][ni] = mfma16(af[mi][kk], bf[ni][kk], acc[mi][ni]);
    __builtin_amdgcn_s_setprio(0);
    PHASE_BAR();

    // ---- P2: read B ni2-3 (4); stage B1(t+1) ----
    #pragma unroll
    for (int ni=2;ni<4;ni++){
      int r = brl + ni*16 + l15;
      #pragma unroll
      for (int kk=0;kk<2;kk++)
        bf[ni][kk] = *(const s16x8*)(Bb + r*128 + (((kk*4+lg) ^ (r&7))<<4));
    }
    if (t+1 < NT) stageB(kn1, bi^1, 1);
    PHASE_BAR(); LGKM0();
    __builtin_amdgcn_s_setprio(1);
    #pragma unroll
    for (int mi=0;mi<4;mi++)
      #pragma unroll
      for (int ni=2;ni<4;ni++)
        #pragma unroll
        for (int kk=0;kk<2;kk++)
          acc[mi][ni] = mfma16(af[mi][kk], bf[ni][kk], acc[mi][ni]);
    __builtin_amdgcn_s_setprio(0);
    PHASE_BAR();

    // ---- P3: read A mi4-7 (8) ----
    #pragma unroll
    for (int mi=4;mi<8;mi++){
      int r = mi*16 + l15;
      #pragma unroll
      for (int kk=0;kk<2;kk++)
        af[mi][kk] = *(const s16x8*)(Ab + r*128 + (((kk*4+lg) ^ (r&7))<<4));
    }
    PHASE_BAR(); LGKM0();
    __builtin_amdgcn_s_setprio(1);
    #pragma unroll
    for (int mi=4;mi<8;mi++)
      #pragma unroll
      for (int ni=2;ni<4;ni++)
        #pragma unroll
        for (int kk=0;kk<2;kk++)
          acc[mi][ni] = mfma16(af[mi][kk], bf[ni][kk], acc[mi][ni]);
    __builtin_amdgcn_s_setprio(0);
    PHASE_BAR();

    // ---- P4: no reads; stage A0,A1(t+2); counted vmcnt ----
    if (t+2 < NT){ stageA(kn2, bi, 0); stageA(kn2, bi, 1); }
    __builtin_amdgcn_s_setprio(1);
    #pragma unroll
    for (int mi=4;mi<8;mi++)
      #pragma unroll
      for (int ni=0;ni<2;ni++)
        #pragma unroll
        for (int kk=0;kk<2;kk++)
          acc[mi][ni] = mfma16(af[mi][kk], bf[ni][kk], acc[mi][ni]);
    __builtin_amdgcn_s_setprio(0);
    if (t < NT-2)      { asm volatile("s_waitcnt vmcnt(4)" ::: "memory"); }
    else if (t == NT-2){ asm volatile("s_waitcnt vmcnt(0)" ::: "memory"); }
    PHASE_BAR();
  }

  #pragma unroll
  for (int mi=0;mi<8;mi++)
    #pragma unroll
    for (int ni=0;ni<4;ni++)
      #pragma unroll
      for (int r=0;r<4;r++){
        size_t row = m0 + wr*128 + mi*16 + lg*4 + r;
        size_t col = n0 + wc*64 + ni*16 + l15;
        C[row*ldc + col] = f2b(acc[mi][ni][r]);
      }
}

// ---------------- GEMM: C[M,N] = A[M,K] * Bt[N,K]^T, bf16 in, f32 acc ----------------
template<bool OUTBF16>
__global__ __launch_bounds__(256) void gemm_bt(const u16* __restrict__ A, const u16* __restrict__ Bt,
                                               void* __restrict__ C, int K, int ldc){
  __shared__ u16 As[128*64];
  __shared__ u16 Bs[128*64];
  const int tid = threadIdx.x, w = tid>>6, l = tid&63;
  const int wm = w>>1, wn = w&1;
  const int l15 = l&15, lg = l>>4, l7 = l&7;
  const size_t m0 = (size_t)blockIdx.y*128, n0 = (size_t)blockIdx.x*128;
  const f32x4 z4 = {0.f,0.f,0.f,0.f};
  f32x4 acc[4][4];
  #pragma unroll
  for (int m=0;m<4;m++)
    #pragma unroll
    for (int n=0;n<4;n++) acc[m][n] = z4;
  const char* AsB = (const char*)As; const char* BsB = (const char*)Bs;
  int colsw[2];
  colsw[0] = (lg*16) ^ (l7<<4);
  colsw[1] = (64 + lg*16) ^ (l7<<4);
  int arow[4], brow[4];
  #pragma unroll
  for (int m=0;m<4;m++){ arow[m] = (wm*64 + m*16 + l15)*128; brow[m] = (wn*64 + m*16 + l15)*128; }
  const int sgl = l7 ^ (l>>3);  // staging pre-swizzled granule
  for (int k0=0;k0<K;k0+=64){
    #pragma unroll
    for (int i=0;i<4;i++){
      int slot = (w*4+i)*64 + l;
      int row = slot>>3;
      glds16(A  + (m0+row)*K + k0 + sgl*8, (u16*)As + slot*8);
      glds16(Bt + (n0+row)*K + k0 + sgl*8, (u16*)Bs + slot*8);
    }
    __syncthreads();
    #pragma unroll
    for (int kb=0;kb<2;kb++){
      s16x8 af[4], bf[4];
      #pragma unroll
      for (int m=0;m<4;m++) af[m] = *(const s16x8*)(AsB + arow[m] + colsw[kb]);
      #pragma unroll
      for (int n=0;n<4;n++) bf[n] = *(const s16x8*)(BsB + brow[n] + colsw[kb]);
      #pragma unroll
      for (int m=0;m<4;m++)
        #pragma unroll
        for (int n=0;n<4;n++)
          acc[m][n] = mfma16(af[m], bf[n], acc[m][n]);
    }
    __syncthreads();
  }
  #pragma unroll
  for (int m=0;m<4;m++)
    #pragma unroll
    for (int n=0;n<4;n++)
      #pragma unroll
      for (int r=0;r<4;r++){
        size_t row = m0 + wm*64 + m*16 + lg*4 + r;
        size_t col = n0 + wn*64 + n*16 + l15;
        if (OUTBF16) ((u16*)C)[row*ldc + col] = f2b(acc[m][n][r]);
        else ((float*)C)[row*ldc + col] = acc[m][n][r];
      }
}

// ---------------- fused RMSNorm + RoPE (+SCALAR for q) ----------------
// one wave per (b,t,head) row; lane l holds elems (l, l+64)
__global__ __launch_bounds__(256) void norm_rope(const u16* __restrict__ qkv, const float* __restrict__ table,
                                                 const float* __restrict__ scale, const int* __restrict__ segpos,
                                                 u16* __restrict__ dst, int nhl2, int colbase, float mult){
  int w = threadIdx.x>>6, l = threadIdx.x&63;
  int rid = blockIdx.x*4 + w;
  int bt = rid >> nhl2;
  int n  = rid & ((1<<nhl2)-1);
  int b = bt >> 11, t = bt & 2047;
  const u16* src = qkv + (size_t)bt*4096 + colbase + n*128;
  float x1 = b2f(src[l]), x2 = b2f(src[64+l]);
  float ss = x1*x1 + x2*x2;
  #pragma unroll
  for (int off=32; off; off>>=1) ss += __shfl_xor(ss, off);
  float rs = rsqrtf(ss*(1.f/128.f) + 1e-6f);
  float v1 = x1*rs*scale[l], v2 = x2*rs*scale[64+l];
  int pos = segpos[bt];
  float2 sc = ((const float2*)table)[pos*64 + l];
  float o1 = (v1*sc.y - v2*sc.x)*mult;
  float o2 = (v2*sc.y + v1*sc.x)*mult;
  u16* d = dst + (((size_t)((b<<nhl2) + n))*2048 + t)*128;
  d[l] = f2b(o1); d[64+l] = f2b(o2);
}

// ---------------- V transpose: vt[(b*8+kv)*128 + d][s] = qkv[b*T+s][3072+kv*128+d] ----------------
__global__ __launch_bounds__(256) void vtr(const u16* __restrict__ qkv, u16* __restrict__ vt){
  __shared__ float t[64][65];
  int bk = blockIdx.z;              // b*8+kv
  int t0 = blockIdx.y*64, d0 = blockIdx.x*64;
  int b = bk>>3, kv = bk&7;
  int tid = threadIdx.x;
  #pragma unroll
  for (int p=0;p<16;p++){ int e = p*256+tid; int r = e>>6, c = e&63;
    t[r][c] = b2f(qkv[(size_t)(b*2048 + t0 + r)*4096 + 3072 + kv*128 + d0 + c]); }
  __syncthreads();
  #pragma unroll
  for (int p=0;p<16;p++){ int e = p*256+tid; int c = e>>6, r = e&63;
    vt[((size_t)bk*128 + d0 + c)*2048 + t0 + r] = f2b(t[r][c]); }
}

// ---------------- flash attention, causal, GQA g=2 ----------------
// Pair-folded for balance: block pair p handles q-tile p (p+1 KV tiles) then
// q-tile 31-p (32-p KV tiles) -> exactly 33 tiles per block. Double-buffered
// KV staging, one barrier per tile. 512 blocks x 4 waves, 2 blocks/CU (72KB LDS).
__global__ __launch_bounds__(256,2) void attn_kern(const u16* __restrict__ qn, const u16* __restrict__ kn,
                                                   const u16* __restrict__ vt, u16* __restrict__ enc){
  __shared__ u16 Ks[2][64*128];   // [s][d], swizzled
  __shared__ u16 Vs[2][64*128];   // [d][s], swizzled
  __shared__ u16 Ps[4*16*64];     // per-wave P, swizzled
  const int idx = blockIdx.x;
  const int pp = idx>>5;               // pair 0..15
  const int hb = idx & 31;
  const int hn = hb & 15, b = hb >> 4;
  const int kv = hn>>1;
  const int tid = threadIdx.x, w = tid>>6, l = tid&63;
  const int l15 = l&15, lg = l>>4;
  const u16* qh = qn + ((size_t)(b*16+hn))*2048*128;
  const u16* kh = kn + ((size_t)(b*8+kv))*2048*128;
  const u16* vh = vt + ((size_t)(b*8+kv))*128*2048;
  const int qbA = pp, qbB = 31-pp;

  int qr0 = qbA*64 + w*16;
  s16x8 qf[4];
  #pragma unroll
  for (int kb=0;kb<4;kb++)
    qf[kb] = *(const s16x8*)(qh + (size_t)(qr0 + l15)*128 + kb*32 + lg*8);

  const f32x4 z4 = {0.f,0.f,0.f,0.f};
  f32x4 o[8];
  #pragma unroll
  for (int dn=0;dn<8;dn++) o[dn] = z4;
  float mrow[4], lp[4];
  #pragma unroll
  for (int r=0;r<4;r++){ mrow[r] = KMASKF; lp[r] = 0.f; }

  const char* KsB0 = (const char*)&Ks[0][0];
  const char* VsB0 = (const char*)&Vs[0][0];
  char* PsB = (char*)Ps + w*2048;

  auto stage = [&](int s0, int bi){
    #pragma unroll
    for (int i=0;i<4;i++){
      int slot = (w*4+i)*64 + l;
      { int row = slot>>4, g = slot&15, gl = g ^ (row&7);
        glds16(kh + (size_t)(s0+row)*128 + gl*8, &Ks[bi][0] + slot*8); }
      { int row = slot>>3, g = slot&7, gl = g ^ (row&7);
        glds16(vh + (size_t)row*2048 + s0 + gl*8, &Vs[bi][0] + slot*8); }
    }
  };

  auto epilogue = [&](int qr){
    #pragma unroll
    for (int r=0;r<4;r++){
      float s = lp[r];
      s += __shfl_xor(s,1); s += __shfl_xor(s,2); s += __shfl_xor(s,4); s += __shfl_xor(s,8);
      lp[r] = 1.f/s;
    }
    #pragma unroll
    for (int dn=0;dn<8;dn++)
      #pragma unroll
      for (int r=0;r<4;r++){
        size_t row = (size_t)b*2048 + qr + lg*4 + r;
        size_t col = hn*128 + dn*16 + l15;
        enc[row*2048 + col] = f2b(o[dn][r]*lp[r]);
      }
  };

  stage(0, 0);
  __syncthreads();

  int cur = 0;
  for (int it=0; it<=32; ++it){
    if (it < 32){
      int s0n = (it+1 <= pp) ? (it+1)*64 : (it-pp)*64;
      stage(s0n, cur^1);
    }
    const int s0 = (it <= pp) ? it*64 : (it-pp-1)*64;
    const char* KsB = KsB0 + cur*16384;
    const char* VsB = VsB0 + cur*16384;

    f32x4 sa[4];
    #pragma unroll
    for (int nc=0;nc<4;nc++) sa[nc] = z4;
    #pragma unroll
    for (int kb=0;kb<4;kb++){
      s16x8 kf[4];
      #pragma unroll
      for (int nc=0;nc<4;nc++){
        int srow = nc*16 + l15;
        int cb = (kb*64 + lg*16) ^ ((srow&7)<<4);
        kf[nc] = *(const s16x8*)(KsB + srow*256 + cb);
      }
      #pragma unroll
      for (int nc=0;nc<4;nc++)
        sa[nc] = mfma16(qf[kb], kf[nc], sa[nc]);
    }
    if (it == pp || it == 32){
      #pragma unroll
      for (int nc=0;nc<4;nc++)
        #pragma unroll
        for (int r=0;r<4;r++){
          int row = qr0 + lg*4 + r;
          int col = s0 + nc*16 + l15;
          if (col > row) sa[nc][r] = KMASKF;
        }
    }
    #pragma unroll
    for (int r=0;r<4;r++){
      float pm = fmaxf(fmaxf(sa[0][r], sa[1][r]), fmaxf(sa[2][r], sa[3][r]));
      pm = fmaxf(pm, __shfl_xor(pm,1));
      pm = fmaxf(pm, __shfl_xor(pm,2));
      pm = fmaxf(pm, __shfl_xor(pm,4));
      pm = fmaxf(pm, __shfl_xor(pm,8));
      float mo = mrow[r];
      float mn = fmaxf(mo, pm);
      float sc = __expf(mo - mn);
      mrow[r] = mn;
      int rowp = lg*4 + r;
      float ls = 0.f;
      #pragma unroll
      for (int nc=0;nc<4;nc++){
        float p = __expf(sa[nc][r] - mn);
        ls += p;
        int cb = ((nc*16 + l15)*2) ^ ((rowp&7)<<4);
        *(u16*)(PsB + rowp*128 + cb) = f2b(p);
      }
      lp[r] = lp[r]*sc + ls;
      #pragma unroll
      for (int dn=0;dn<8;dn++) o[dn][r] *= sc;
    }
    asm volatile("" ::: "memory");   // order P ds_writes before PV ds_reads (same wave)
    #pragma unroll
    for (int kb=0;kb<2;kb++){
      int rowp = l15;
      int cbp = (kb*64 + lg*16) ^ ((rowp&7)<<4);
      s16x8 pf = *(const s16x8*)(PsB + rowp*128 + cbp);
      #pragma unroll
      for (int dn=0;dn<8;dn++){
        int vrow = dn*16 + l15;
        int cb = (kb*64 + lg*16) ^ ((vrow&7)<<4);
        s16x8 vf = *(const s16x8*)(VsB + vrow*128 + cb);
        o[dn] = mfma16(pf, vf, o[dn]);
      }
    }
    if (it == pp){
      // finish q-tile A: write it out, reset state, switch to q-tile B
      epilogue(qr0);
      qr0 = qbB*64 + w*16;
      #pragma unroll
      for (int kb=0;kb<4;kb++)
        qf[kb] = *(const s16x8*)(qh + (size_t)(qr0 + l15)*128 + kb*32 + lg*8);
      #pragma unroll
      for (int dn=0;dn<8;dn++) o[dn] = z4;
      #pragma unroll
      for (int r=0;r<4;r++){ mrow[r] = KMASKF; lp[r] = 0.f; }
    }
    __syncthreads();
    cur ^= 1;
  }
  epilogue(qr0);
}

extern "C" void kernel_launch(void* const* d_in, const int* in_sizes, int n_in,
                              void* d_out, int out_size, void* d_ws, size_t ws_size,
                              hipStream_t stream){
  const float* x      = (const float*)d_in[0];
  const int*   segpos = (const int*)d_in[1];
  // d_in[2] = attn_mask: structurally causal (tril) — handled analytically in attn_kern
  const float* qw     = (const float*)d_in[3];
  const float* kvw    = (const float*)d_in[4];
  const float* ow     = (const float*)d_in[5];
  const float* qs     = (const float*)d_in[6];
  const float* ks     = (const float*)d_in[7];
  float* out = (float*)d_out;

  char* ws = (char*)d_ws;
  size_t off = 0;
  auto alloc = [&](size_t bytes)->void*{ void* p = ws + off; off += (bytes + 255) & ~(size_t)255; return p; };
  u16*   xb    = (u16*)alloc((size_t)4096*2048*2);    // x bf16
  u16*   wqkvt = (u16*)alloc((size_t)4096*2048*2);    // combined qkv weight, B^T
  u16*   wot   = (u16*)alloc((size_t)2048*2048*2);    // o_w^T
  u16*   qkv   = (u16*)alloc((size_t)4096*4096*2);    // qkv projections bf16
  u16*   qn    = (u16*)alloc((size_t)2*16*2048*128*2);// normed+roped q (SCALAR folded)
  u16*   kn    = (u16*)alloc((size_t)2*8*2048*128*2); // normed+roped k
  u16*   vt    = (u16*)alloc((size_t)2*8*128*2048*2); // v transposed [d][s]
  u16*   enc   = (u16*)alloc((size_t)4096*2048*2);    // attention output bf16
  float* table = (float*)alloc((size_t)2048*64*2*4);  // rope sin/cos

  cvt_f32_bf16<<<4096,256,0,stream>>>(x, xb);
  build_wqkvt<<<dim3(2,32,32),256,0,stream>>>(qw, kvw, wqkvt);
  tr2048<<<dim3(32,32),256,0,stream>>>(ow, wot);
  rope_table<<<512,256,0,stream>>>(table);
  gemm256<<<256,512,0,stream>>>(xb, wqkvt, qkv, 2048, 4096);                   // qkv proj, bf16 out
  norm_rope<<<16384,256,0,stream>>>(qkv, table, qs, segpos, qn, 4, 0,    SCALAR_F);
  norm_rope<<<8192, 256,0,stream>>>(qkv, table, ks, segpos, kn, 3, 2048, 1.0f);
  vtr<<<dim3(2,32,16),256,0,stream>>>(qkv, vt);
  attn_kern<<<512,256,0,stream>>>(qn, kn, vt, enc);
  gemm_bt<false><<<dim3(16,32),256,0,stream>>>(enc, wot, out, 2048, 2048);     // f32 out
}